// Round 3
// baseline (5787.169 us; speedup 1.0000x reference)
//
#include <hip/hip_runtime.h>
#include <math.h>

#define BB   4
#define SS   64
#define DD   512
#define HH   8
#define DHH  64
#define DFFF 2048
#define LL   2
#define VV   32128
#define TT   16
#define EPSV 1e-6f
#define NEGB (-1e9f)
#define NTHR 256
#define NCH  502             // 502 * 64 = 32128 vocab cols (dmerge chunks)
#define NCH2 1004            // 1004 * 32 = 32128 vocab cols (lmhead chunks)
#define STS2 1024            // stride for per-chunk stat arrays

#define BSDc ((size_t)131072)    // B*S*D
#define DD2c ((size_t)262144)    // D*D

// ===================== encoder kernels ====================================

__global__ __launch_bounds__(NTHR) void k_embed(const int* __restrict__ ids,
        const float* __restrict__ emb, float* __restrict__ xe, float* __restrict__ xd) {
    int blk = blockIdx.x, tid = threadIdx.x;
    int id = ids[blk];
    const float* src = emb + (size_t)id * DD;
    float* dst = xe + (size_t)blk * DD;
    for (int k = tid; k < DD; k += NTHR) dst[k] = src[k];
    if (blk < BB) {
        float* xdp = xd + (size_t)blk * DD;
        for (int k = tid; k < DD; k += NTHR) xdp[k] = emb[k];   // emb[PAD=0]
    }
}

// 64x64 GEMM tile; A is [256 x K], W is [K x N]
__device__ __forceinline__ void d_gemm_tile(const float* __restrict__ A, const float* __restrict__ W,
        float* __restrict__ C, const float* __restrict__ res,
        int K, int N, int relu, int tile, float* sm) {
    float* As = sm;                 // [16][65]
    float* Ws = sm + 16 * 65;       // [16][64]
    int tid = threadIdx.x;
    int tr = tid >> 4, tc = tid & 15;
    int nb = N >> 6;
    int row0 = (tile / nb) * 64, col0 = (tile % nb) * 64;
    float acc[4][4] = {};
    for (int k0 = 0; k0 < K; k0 += 16) {
        for (int i = tid; i < 64 * 16; i += NTHR) {
            int r = i >> 4, kk = i & 15;
            As[kk * 65 + r] = A[(size_t)(row0 + r) * K + k0 + kk];
        }
        for (int i = tid; i < 16 * 64; i += NTHR) {
            int kk = i >> 6, c = i & 63;
            Ws[kk * 64 + c] = W[(size_t)(k0 + kk) * N + col0 + c];
        }
        __syncthreads();
        #pragma unroll
        for (int kk = 0; kk < 16; kk++) {
            float a[4], b[4];
            #pragma unroll
            for (int j = 0; j < 4; j++) { a[j] = As[kk * 65 + tr * 4 + j]; b[j] = Ws[kk * 64 + tc * 4 + j]; }
            #pragma unroll
            for (int r = 0; r < 4; r++)
                #pragma unroll
                for (int c = 0; c < 4; c++) acc[r][c] += a[r] * b[c];
        }
        __syncthreads();
    }
    #pragma unroll
    for (int r = 0; r < 4; r++)
        #pragma unroll
        for (int c = 0; c < 4; c++) {
            int gr = row0 + tr * 4 + r, gc = col0 + tc * 4 + c;
            float v = acc[r][c];
            if (res) v += res[(size_t)gr * N + gc];
            if (relu) v = fmaxf(v, 0.f);
            C[(size_t)gr * N + gc] = v;
        }
}

// same, but A is raw x: apply per-row RMS scale; ln folded into W rows. K=512.
__device__ __forceinline__ void d_gemm_rms(const float* __restrict__ A, const float* __restrict__ lnw,
        const float* __restrict__ W, float* __restrict__ C, const float* __restrict__ res,
        int N, int relu, int tile, float* sm) {
    float* As  = sm;                 // [16][65]
    float* Ws  = sm + 16 * 65;       // [16][64]
    float* ps  = sm + 2064;          // 256 partials
    float* scl = sm + 2320;          // 64 row scales
    int tid = threadIdx.x;
    int tr = tid >> 4, tc = tid & 15;
    int nb = N >> 6;
    int row0 = (tile / nb) * 64, col0 = (tile % nb) * 64;
    {   // row RMS scales: 4 threads per row
        int r = tid >> 2, p = tid & 3;
        const float4* xr = (const float4*)(A + (size_t)(row0 + r) * 512 + p * 128);
        float s = 0.f;
        #pragma unroll
        for (int i = 0; i < 32; i++) { float4 v = xr[i]; s += v.x*v.x + v.y*v.y + v.z*v.z + v.w*v.w; }
        ps[tid] = s;
    }
    __syncthreads();
    if (tid < 64) {
        float s = ps[tid * 4] + ps[tid * 4 + 1] + ps[tid * 4 + 2] + ps[tid * 4 + 3];
        scl[tid] = 1.0f / sqrtf(s / 512.f + EPSV);
    }
    __syncthreads();
    float acc[4][4] = {};
    for (int k0 = 0; k0 < 512; k0 += 16) {
        for (int i = tid; i < 64 * 16; i += NTHR) {
            int r = i >> 4, kk = i & 15;
            As[kk * 65 + r] = A[(size_t)(row0 + r) * 512 + k0 + kk] * scl[r];
        }
        for (int i = tid; i < 16 * 64; i += NTHR) {
            int kk = i >> 6, c = i & 63;
            Ws[kk * 64 + c] = W[(size_t)(k0 + kk) * N + col0 + c] * lnw[k0 + kk];
        }
        __syncthreads();
        #pragma unroll
        for (int kk = 0; kk < 16; kk++) {
            float a[4], b[4];
            #pragma unroll
            for (int j = 0; j < 4; j++) { a[j] = As[kk * 65 + tr * 4 + j]; b[j] = Ws[kk * 64 + tc * 4 + j]; }
            #pragma unroll
            for (int r = 0; r < 4; r++)
                #pragma unroll
                for (int c = 0; c < 4; c++) acc[r][c] += a[r] * b[c];
        }
        __syncthreads();
    }
    #pragma unroll
    for (int r = 0; r < 4; r++)
        #pragma unroll
        for (int c = 0; c < 4; c++) {
            int gr = row0 + tr * 4 + r, gc = col0 + tc * 4 + c;
            float v = acc[r][c];
            if (res) v += res[(size_t)gr * N + gc];
            if (relu) v = fmaxf(v, 0.f);
            C[(size_t)gr * N + gc] = v;
        }
}

__global__ __launch_bounds__(NTHR) void k_gemm(const float* __restrict__ A, const float* __restrict__ W,
        float* __restrict__ C, const float* __restrict__ res, int K, int N, int relu) {
    __shared__ float sm[16 * 65 + 16 * 64];
    d_gemm_tile(A, W, C, res, K, N, relu, blockIdx.x, sm);
}

__global__ __launch_bounds__(NTHR) void k_gemm_rms(const float* __restrict__ A, const float* __restrict__ lnw,
        const float* __restrict__ W, float* __restrict__ C, const float* __restrict__ res,
        int N, int relu) {
    __shared__ float sm[2384];
    d_gemm_rms(A, lnw, W, C, res, N, relu, blockIdx.x, sm);
}

__global__ __launch_bounds__(NTHR) void k_qkv_f(const float* __restrict__ A, const float* __restrict__ lnw,
        const float* __restrict__ wq, const float* __restrict__ wk, const float* __restrict__ wv,
        float* __restrict__ qkv) {
    __shared__ float sm[2384];
    int m = blockIdx.x >> 5, t2 = blockIdx.x & 31;
    const float* W = (m == 0) ? wq : (m == 1 ? wk : wv);
    d_gemm_rms(A, lnw, W, qkv + (size_t)m * BSDc, nullptr, 512, 0, t2, sm);
}

__global__ __launch_bounds__(NTHR) void k_ckcv_f(const float* __restrict__ A, const float* __restrict__ lnw,
        const float* __restrict__ wck, const float* __restrict__ wcv,
        float* __restrict__ cK, float* __restrict__ cV) {
    __shared__ float sm[2384];
    int m = blockIdx.x >> 5, t2 = blockIdx.x & 31;
    const float* W = (m < 2) ? (wck + (size_t)m * DD2c) : (wcv + (size_t)(m - 2) * DD2c);
    float* O = (m < 2) ? (cK + (size_t)m * BSDc) : (cV + (size_t)(m - 2) * BSDc);
    d_gemm_rms(A, lnw, W, O, nullptr, 512, 0, t2, sm);
}

__global__ __launch_bounds__(NTHR) void k_eattn(const float* __restrict__ qkv,
        const float* __restrict__ mask, float* __restrict__ o) {
    __shared__ float sm[3 * 64 * 65];
    int job = blockIdx.x;
    int b = job / HH, h = job % HH;
    int tid = threadIdx.x;
    int lane = tid & 63, wave = tid >> 6;
    float* qq = sm;
    float* kk = sm + 64 * 65;
    float* vv = sm + 2 * 64 * 65;
    for (int i = tid; i < SS * DHH; i += NTHR) {
        int s = i >> 6, d = i & 63;
        size_t src = (size_t)(b * SS + s) * DD + h * DHH + d;
        qq[s * 65 + d] = qkv[src];
        kk[s * 65 + d] = qkv[BSDc + src];
        vv[s * 65 + d] = qkv[2 * BSDc + src];
    }
    __syncthreads();
    float bias = (1.0f - mask[b * SS + lane]) * NEGB;
    for (int r = 0; r < 16; r++) {
        int s = wave * 16 + r;
        float sc = 0.f;
        for (int i = 0; i < DHH; i++) sc += qq[s * 65 + i] * kk[lane * 65 + i];
        sc = sc * 0.125f + bias;
        float m = sc;
        for (int o2 = 32; o2 > 0; o2 >>= 1) m = fmaxf(m, __shfl_xor(m, o2));
        float e = expf(sc - m);
        float sum = e;
        for (int o2 = 32; o2 > 0; o2 >>= 1) sum += __shfl_xor(sum, o2);
        float p = e / sum;
        float acc = 0.f;
        for (int t2 = 0; t2 < SS; t2++) acc += __shfl(p, t2) * vv[t2 * 65 + lane];
        o[(size_t)(b * SS + s) * DD + h * DHH + lane] = acc;
    }
}

// ===================== decode kernels =====================================

// GEMV core on an LDS-resident hAT[K][4]: cols [cb*NC, +NC) of W[K][N]
template<int K, int NC>
__device__ __forceinline__ void gemv_ldsA(const float* hAT, const float* __restrict__ W,
        float* __restrict__ O, int ostr, int N, const float* __restrict__ res, int relu,
        int cb, float* red) {
    constexpr int C4N = NC / 4;            // float4 col-threads
    constexpr int KSN = NTHR / C4N;        // k-slices
    constexpr int KC  = K / KSN;           // k per slice
    const int tid = threadIdx.x;
    const int c4 = tid % C4N, ks = tid / C4N;
    const float4* W4 = (const float4*)W;
    const int col0 = cb * NC;
    float acc[4][4] = {};
    const int kb = ks * KC;
    #pragma unroll 8
    for (int kk = 0; kk < KC; kk++) {
        int k = kb + kk;
        float4 w4 = W4[(size_t)k * (N >> 2) + (col0 >> 2) + c4];
        float4 h4 = *(const float4*)(hAT + (size_t)k * 4);
        float hb[4] = {h4.x, h4.y, h4.z, h4.w};
        float wb[4] = {w4.x, w4.y, w4.z, w4.w};
        #pragma unroll
        for (int b = 0; b < 4; b++)
            #pragma unroll
            for (int ci = 0; ci < 4; ci++) acc[b][ci] += hb[b] * wb[ci];
    }
    {
        float* rp = red + (size_t)ks * (NC * 4) + c4 * 4;
        #pragma unroll
        for (int b = 0; b < 4; b++)
            #pragma unroll
            for (int ci = 0; ci < 4; ci++) rp[b * NC + ci] = acc[b][ci];
    }
    __syncthreads();
    for (int o = tid; o < 4 * NC; o += NTHR) {
        int b = o / NC, c = o % NC;
        float v = 0.f;
        #pragma unroll
        for (int k2 = 0; k2 < KSN; k2++) v += red[(size_t)k2 * (NC * 4) + o];
        if (res) v += res[(size_t)b * ostr + col0 + c];
        if (relu) v = fmaxf(v, 0.f);
        O[(size_t)b * ostr + col0 + c] = v;
    }
}

// small-M GEMV: optional RMSNorm(A rows)*ln -> hAT, then gemv_ldsA
template<int K, int NC>
__device__ __forceinline__ void gemv_dev(const float* __restrict__ A, const float* __restrict__ ln,
        const float* __restrict__ W, float* __restrict__ O, int ostr, int N,
        const float* __restrict__ res, int relu, int cb, float* sm) {
    const int tid = threadIdx.x, lane = tid & 63, wv = tid >> 6;
    float* hAT = sm;                       // K*4
    float* red = sm + K * 4;               // 4096
    float* scl = sm + K * 4 + 4096;        // 4
    if (ln) {
        const float* ar = A + (size_t)wv * K;
        float loc = 0.f;
        for (int k = lane; k < K; k += 64) { float x = ar[k]; loc += x * x; }
        for (int o = 32; o > 0; o >>= 1) loc += __shfl_xor(loc, o);
        if (lane == 0) scl[wv] = 1.0f / sqrtf(loc / K + EPSV);
    }
    __syncthreads();
    float s0 = ln ? scl[0] : 1.f, s1 = ln ? scl[1] : 1.f;
    float s2 = ln ? scl[2] : 1.f, s3 = ln ? scl[3] : 1.f;
    for (int k = tid; k < K; k += NTHR) {
        float lw = ln ? ln[k] : 1.0f;
        float4 h;
        h.x = A[k] * s0 * lw;
        h.y = A[K + k] * s1 * lw;
        h.z = A[2 * K + k] * s2 * lw;
        h.w = A[3 * K + k] * s3 * lw;
        *(float4*)(hAT + (size_t)k * 4) = h;
    }
    __syncthreads();
    gemv_ldsA<K, NC>(hAT, W, O, ostr, N, res, relu, cb, red);
}

template<int K, int NC>
__global__ __launch_bounds__(NTHR) void k_gemv(const float* __restrict__ A, const float* __restrict__ ln,
        const float* __restrict__ W, float* __restrict__ O, int ostr, int N,
        const float* __restrict__ res, int relu) {
    __shared__ float sm[K * 4 + 4096 + 4];
    gemv_dev<K, NC>(A, ln, W, O, ostr, N, res, relu, blockIdx.x, sm);
}

__global__ __launch_bounds__(NTHR) void k_dqkv(const float* __restrict__ xc, const float* __restrict__ ln1,
        const float* __restrict__ wq, const float* __restrict__ wk, const float* __restrict__ wv,
        float* __restrict__ dq, float* __restrict__ sKw, float* __restrict__ sVw) {
    __shared__ float sm[512 * 4 + 4096 + 4];
    int m = blockIdx.x >> 5, cb = blockIdx.x & 31;
    const float* W = (m == 0) ? wq : (m == 1 ? wk : wv);
    float* O = (m == 0) ? dq : (m == 1 ? sKw : sVw);
    int ostr = (m == 0) ? DD : TT * DD;
    gemv_dev<512, 16>(xc, ln1, W, O, ostr, 512, nullptr, 0, cb, sm);
}

// fused decoder self-attn + so-projection (+residual into xc)
__global__ __launch_bounds__(NTHR) void k_attnso(const float* __restrict__ dq,
        const float* __restrict__ sKl, const float* __restrict__ sVl,
        const float* __restrict__ Wso, float* __restrict__ xc, int p) {
    __shared__ float dqS[2048];
    __shared__ float dT[2048];
    __shared__ float red[4096];
    int tid = threadIdx.x, lane = tid & 63, b = tid >> 6;
    for (int k = tid; k < BB * DD; k += NTHR) dqS[k] = dq[k];
    __syncthreads();
    for (int h = 0; h < HH; h++) {
        float sc = -1e30f;
        if (lane <= p) {
            const float* kr = sKl + ((size_t)b * TT + lane) * DD + h * DHH;
            float s2 = 0.f;
            #pragma unroll 16
            for (int i = 0; i < DHH; i++) s2 += dqS[b * DD + h * DHH + i] * kr[i];
            sc = s2 * 0.125f;
        }
        float m = sc;
        for (int o2 = 32; o2 > 0; o2 >>= 1) m = fmaxf(m, __shfl_xor(m, o2));
        float e = (lane <= p) ? expf(sc - m) : 0.f;
        float sum = e;
        for (int o2 = 32; o2 > 0; o2 >>= 1) sum += __shfl_xor(sum, o2);
        float pr = e / sum;
        float acc = 0.f;
        for (int j = 0; j <= p; j++) {
            float pj = __shfl(pr, j);
            acc += pj * sVl[((size_t)b * TT + j) * DD + h * DHH + lane];
        }
        dT[(h * DHH + lane) * 4 + b] = acc;
    }
    __syncthreads();
    gemv_ldsA<512, 16>(dT, Wso, xc, DD, 512, xc, 0, blockIdx.x, red);
}

// fused decoder cross-attn + co-projection (+residual into xc)
__global__ __launch_bounds__(NTHR) void k_crossco(const float* __restrict__ dq,
        const float* __restrict__ cKl, const float* __restrict__ cVl,
        const float* __restrict__ mask, const float* __restrict__ Wco,
        float* __restrict__ xc) {
    __shared__ float dqS[2048];
    __shared__ float dT[2048];
    __shared__ float red[4096];
    int tid = threadIdx.x, lane = tid & 63, b = tid >> 6;
    for (int k = tid; k < BB * DD; k += NTHR) dqS[k] = dq[k];
    __syncthreads();
    float bias = (1.0f - mask[b * SS + lane]) * NEGB;
    for (int h = 0; h < HH; h++) {
        const float* kr = cKl + ((size_t)b * SS + lane) * DD + h * DHH;
        float s2 = 0.f;
        #pragma unroll 16
        for (int i = 0; i < DHH; i++) s2 += dqS[b * DD + h * DHH + i] * kr[i];
        float sc = s2 * 0.125f + bias;
        float m = sc;
        for (int o2 = 32; o2 > 0; o2 >>= 1) m = fmaxf(m, __shfl_xor(m, o2));
        float e = expf(sc - m);
        float sum = e;
        for (int o2 = 32; o2 > 0; o2 >>= 1) sum += __shfl_xor(sum, o2);
        float pr = e / sum;
        float acc = 0.f;
        for (int j = 0; j < SS; j++) {
            float pj = __shfl(pr, j);
            acc += pj * cVl[((size_t)b * SS + j) * DD + h * DHH + lane];
        }
        dT[(h * DHH + lane) * 4 + b] = acc;
    }
    __syncthreads();
    gemv_ldsA<512, 16>(dT, Wco, xc, DD, 512, xc, 0, blockIdx.x, red);
}

// lm_head chunk (blocks 0..1003, 32 cols each) + stats; block 1004 zeroes xn
__global__ __launch_bounds__(NTHR) void k_lmhead(const float* __restrict__ xc, float* __restrict__ xn,
        const float* __restrict__ lnf, const float* __restrict__ Wlm,
        float* __restrict__ lgb, float* __restrict__ stm, float* __restrict__ sts,
        int* __restrict__ stix) {
    int blk = blockIdx.x, tid = threadIdx.x, lane = tid & 63, wave = tid >> 6;
    if (blk >= NCH2) {
        for (int k = tid; k < BB * DD; k += NTHR) xn[k] = 0.f;
        return;
    }
    __shared__ float hAT[2048];
    __shared__ float red[4096];
    __shared__ float msc[4];
    __shared__ float lgl[128];
    for (int k = tid; k < DD; k += NTHR) {
        float4 r;
        r.x = xc[k];          r.y = xc[DD + k];
        r.z = xc[2 * DD + k]; r.w = xc[3 * DD + k];
        *(float4*)(hAT + (size_t)k * 4) = r;
    }
    __syncthreads();
    {
        float loc = 0.f;
        for (int k = lane; k < DD; k += 64) { float x = hAT[k * 4 + wave]; loc += x * x; }
        for (int o = 32; o > 0; o >>= 1) loc += __shfl_xor(loc, o);
        if (lane == 0) msc[wave] = 1.0f / sqrtf(loc / DD + EPSV);
    }
    __syncthreads();
    float s0 = msc[0], s1 = msc[1], s2 = msc[2], s3 = msc[3];
    for (int k = tid; k < DD; k += NTHR) {
        float lw = lnf[k];
        float4 r = *(float4*)(hAT + (size_t)k * 4);
        r.x *= s0 * lw; r.y *= s1 * lw; r.z *= s2 * lw; r.w *= s3 * lw;
        *(float4*)(hAT + (size_t)k * 4) = r;
    }
    __syncthreads();
    {   // 32 cols: 8 c4-threads x 32 k-slices of 16
        int c4 = tid & 7, ks = tid >> 3;
        const float4* W4 = (const float4*)Wlm;
        float acc[4][4] = {};
        int kb = ks * 16;
        #pragma unroll
        for (int kk = 0; kk < 16; kk++) {
            int k = kb + kk;
            float4 w4 = W4[(size_t)k * (VV >> 2) + blk * 8 + c4];
            float4 h4 = *(float4*)(hAT + (size_t)k * 4);
            float hb[4] = {h4.x, h4.y, h4.z, h4.w};
            float wb[4] = {w4.x, w4.y, w4.z, w4.w};
            #pragma unroll
            for (int b = 0; b < 4; b++)
                #pragma unroll
                for (int ci = 0; ci < 4; ci++) acc[b][ci] += hb[b] * wb[ci];
        }
        float* rp = red + ks * 128 + c4 * 4;
        #pragma unroll
        for (int b = 0; b < 4; b++)
            #pragma unroll
            for (int ci = 0; ci < 4; ci++) rp[b * 32 + ci] = acc[b][ci];
    }
    __syncthreads();
    if (tid < 128) {
        float v = 0.f;
        #pragma unroll
        for (int k2 = 0; k2 < 32; k2++) v += red[k2 * 128 + tid];
        lgl[tid] = v;
        lgb[(size_t)(tid >> 5) * VV + blk * 32 + (tid & 31)] = v;
    }
    __syncthreads();
    {
        int b = wave;
        float v0 = (lane < 32) ? lgl[b * 32 + lane] : -1e30f;
        int ix = (lane < 32) ? blk * 32 + lane : 0x7fffffff;
        float mx = v0;
        for (int o = 32; o > 0; o >>= 1) {
            float om = __shfl_xor(mx, o); int oi = __shfl_xor(ix, o);
            if (om > mx || (om == mx && oi < ix)) { mx = om; ix = oi; }
        }
        float s = (lane < 32) ? expf(v0 - mx) : 0.f;
        for (int o = 32; o > 0; o >>= 1) s += __shfl_xor(s, o);
        if (lane == 0) {
            stm[b * STS2 + blk] = mx;
            sts[b * STS2 + blk] = s;
            stix[b * STS2 + blk] = ix;
        }
    }
}

// merge stats + probs out + soft-emb partial -> xn; block 502 writes preds
__global__ __launch_bounds__(NTHR) void k_dmerge(const float* __restrict__ lgb,
        const float* __restrict__ stm, const float* __restrict__ sts, const int* __restrict__ stix,
        const float* __restrict__ emb, float* __restrict__ out, float* __restrict__ xn, int tt) {
    __shared__ float mM[8];
    __shared__ int jS[4];
    __shared__ float pT[256];
    __shared__ float red[4096];
    int blk = blockIdx.x, tid = threadIdx.x, lane = tid & 63, wave = tid >> 6;
    {   // merge per b (wave b)
        int b = wave;
        float M = -1e30f, S = 0.f; int jb = 0;
        for (int j = lane; j < NCH2; j += 64) {
            float mj = stm[b * STS2 + j], sj = sts[b * STS2 + j];
            if (mj > M) { S = S * expf(M - mj) + sj; M = mj; jb = j; }
            else        { S += sj * expf(mj - M); }
        }
        for (int o = 32; o > 0; o >>= 1) {
            float Mo = __shfl_xor(M, o), So = __shfl_xor(S, o);
            int jo = __shfl_xor(jb, o);
            if (Mo > M || (Mo == M && jo < jb)) { S = S * expf(M - Mo) + So; M = Mo; jb = jo; }
            else { S += So * expf(Mo - M); }
        }
        if (lane == 0) { mM[b] = M; mM[4 + b] = S; jS[b] = jb; }
    }
    __syncthreads();
    if (blk < NCH) {
        {   // final probs for this chunk: write out + stash transposed
            int b = tid >> 6, c = tid & 63;
            float lg = lgb[(size_t)b * VV + blk * 64 + c];
            float p = expf(lg - mM[b]) / mM[4 + b];
            out[((size_t)b * TT + tt) * VV + blk * 64 + c] = p;
            pT[c * 4 + b] = p;
        }
        __syncthreads();
        {   // emb chunk (same 64 vocab rows as this block's logits)
            int c4 = tid & 127, rs = tid >> 7;
            const float4* E4 = (const float4*)emb;
            float4 a0 = {0,0,0,0}, a1 = a0, a2 = a0, a3 = a0;
            int rb = rs * 32;
            #pragma unroll 8
            for (int r = 0; r < 32; r++) {
                int row = rb + r;
                float4 e4 = E4[((size_t)(blk * 64 + row)) * 128 + c4];
                float4 p4 = *(float4*)(pT + row * 4);
                a0.x += p4.x * e4.x; a0.y += p4.x * e4.y; a0.z += p4.x * e4.z; a0.w += p4.x * e4.w;
                a1.x += p4.y * e4.x; a1.y += p4.y * e4.y; a1.z += p4.y * e4.z; a1.w += p4.y * e4.w;
                a2.x += p4.z * e4.x; a2.y += p4.z * e4.y; a2.z += p4.z * e4.z; a2.w += p4.z * e4.w;
                a3.x += p4.w * e4.x; a3.y += p4.w * e4.y; a3.z += p4.w * e4.z; a3.w += p4.w * e4.w;
            }
            float* rp = red + rs * 2048 + c4 * 4;
            rp[0]        = a0.x; rp[1]        = a0.y; rp[2]        = a0.z; rp[3]        = a0.w;
            rp[512 + 0]  = a1.x; rp[512 + 1]  = a1.y; rp[512 + 2]  = a1.z; rp[512 + 3]  = a1.w;
            rp[1024 + 0] = a2.x; rp[1024 + 1] = a2.y; rp[1024 + 2] = a2.z; rp[1024 + 3] = a2.w;
            rp[1536 + 0] = a3.x; rp[1536 + 1] = a3.y; rp[1536 + 2] = a3.z; rp[1536 + 3] = a3.w;
        }
        __syncthreads();
        #pragma unroll
        for (int i = 0; i < 8; i++) {
            int o = tid + i * 256;
            atomicAdd(xn + o, red[o] + red[2048 + o]);
        }
    } else {
        if (tid < 4) {   // pred flags
            int col = stix[tid * STS2 + jS[tid]];
            out[(size_t)BB * TT * VV + tid * TT + tt] = (col == 0) ? 1.0f : 0.0f;
        }
    }
}

// ===================== launch =============================================
extern "C" void kernel_launch(void* const* d_in, const int* in_sizes, int n_in,
                              void* d_out, int out_size, void* d_ws, size_t ws_size,
                              hipStream_t stream) {
    const int*   ids     = (const int*)  d_in[0];
    const float* mask    = (const float*)d_in[1];
    const float* emb     = (const float*)d_in[2];
    const float* enc_wq  = (const float*)d_in[3];
    const float* enc_wk  = (const float*)d_in[4];
    const float* enc_wv  = (const float*)d_in[5];
    const float* enc_wo  = (const float*)d_in[6];
    const float* enc_ln1 = (const float*)d_in[7];
    const float* enc_w1  = (const float*)d_in[8];
    const float* enc_w2  = (const float*)d_in[9];
    const float* enc_ln2 = (const float*)d_in[10];
    const float* enc_lnf = (const float*)d_in[11];
    const float* dec_sq  = (const float*)d_in[12];
    const float* dec_sk  = (const float*)d_in[13];
    const float* dec_sv  = (const float*)d_in[14];
    const float* dec_so  = (const float*)d_in[15];
    const float* dec_ln1 = (const float*)d_in[16];
    const float* dec_cq  = (const float*)d_in[17];
    const float* dec_ck  = (const float*)d_in[18];
    const float* dec_cv  = (const float*)d_in[19];
    const float* dec_co  = (const float*)d_in[20];
    const float* dec_ln2 = (const float*)d_in[21];
    const float* dec_w1  = (const float*)d_in[22];
    const float* dec_w2  = (const float*)d_in[23];
    const float* dec_ln3 = (const float*)d_in[24];
    const float* dec_lnf = (const float*)d_in[25];
    const float* lm_head = (const float*)d_in[26];
    float* out = (float*)d_out;

    // ---- workspace layout (floats) ----
    float* ws    = (float*)d_ws;
    float* xe    = ws;                                  // 131072
    float* qkv   = xe + BSDc;                           // 393216
    float* attb  = qkv + 3 * BSDc;                      // 131072
    float* ffbuf = attb + BSDc;                         // 524288
    float* cK    = ffbuf + (size_t)BB * SS * DFFF;      // 262144
    float* cV    = cK + LL * BSDc;                      // 262144
    float* sK    = cV + LL * BSDc;                      // 65536
    float* sV    = sK + (size_t)LL * BB * TT * DD;      // 65536
    float* xdA   = sV + (size_t)LL * BB * TT * DD;      // 2048
    float* xdB   = xdA + 2048;                          // 2048
    float* dq    = xdB + 2048;                          // 2048
    float* dff   = dq + 2048;                           // 8192
    float* stm   = dff + 8192;                          // 4096
    float* sts   = stm + 4 * STS2;                      // 4096
    int*   stix  = (int*)(sts + 4 * STS2);              // 4096
    float* lgb   = (float*)(stix) + 4 * STS2;           // 128512 (4*VV)

    // ---------- encoder ----------
    k_embed<<<256, NTHR, 0, stream>>>(ids, emb, xe, xdA);
    for (int l = 0; l < LL; l++) {
        k_qkv_f<<<96, NTHR, 0, stream>>>(xe, enc_ln1 + (size_t)l * DD,
                enc_wq + (size_t)l * DD2c, enc_wk + (size_t)l * DD2c, enc_wv + (size_t)l * DD2c, qkv);
        k_eattn<<<32, NTHR, 0, stream>>>(qkv, mask, attb);
        k_gemm<<<32, NTHR, 0, stream>>>(attb, enc_wo + (size_t)l * DD2c, xe, xe, 512, 512, 0);
        k_gemm_rms<<<128, NTHR, 0, stream>>>(xe, enc_ln2 + (size_t)l * DD,
                enc_w1 + (size_t)l * DD * DFFF, ffbuf, nullptr, 2048, 1);
        k_gemm<<<32, NTHR, 0, stream>>>(ffbuf, enc_w2 + (size_t)l * DFFF * DD, xe, xe, 2048, 512, 0);
    }
    k_ckcv_f<<<128, NTHR, 0, stream>>>(xe, enc_lnf, dec_ck, dec_cv, cK, cV);

    // ---------- decode ----------
    for (int tt = 0; tt < TT; tt++) {
        float* xc = (tt & 1) ? xdB : xdA;
        float* xn = (tt & 1) ? xdA : xdB;
        for (int l = 0; l < LL; l++) {
            k_dqkv<<<96, NTHR, 0, stream>>>(xc, dec_ln1 + (size_t)l * DD,
                    dec_sq + (size_t)l * DD2c, dec_sk + (size_t)l * DD2c, dec_sv + (size_t)l * DD2c,
                    dq, sK + ((size_t)l * BB * TT + tt) * DD, sV + ((size_t)l * BB * TT + tt) * DD);
            k_attnso<<<32, NTHR, 0, stream>>>(dq, sK + (size_t)l * BB * TT * DD,
                    sV + (size_t)l * BB * TT * DD, dec_so + (size_t)l * DD2c, xc, tt);
            k_gemv<512, 16><<<32, NTHR, 0, stream>>>(xc, dec_ln2 + (size_t)l * DD,
                    dec_cq + (size_t)l * DD2c, dq, DD, 512, nullptr, 0);
            k_crossco<<<32, NTHR, 0, stream>>>(dq, cK + (size_t)l * BSDc, cV + (size_t)l * BSDc,
                    mask, dec_co + (size_t)l * DD2c, xc);
            k_gemv<512, 16><<<128, NTHR, 0, stream>>>(xc, dec_ln3 + (size_t)l * DD,
                    dec_w1 + (size_t)l * DD * DFFF, dff, DFFF, DFFF, nullptr, 1);
            k_gemv<2048, 8><<<64, NTHR, 0, stream>>>(dff, nullptr, dec_w2 + (size_t)l * DFFF * DD,
                    xc, DD, 512, xc, 0);
        }
        k_lmhead<<<NCH2 + 1, NTHR, 0, stream>>>(xc, xn, dec_lnf, lm_head, lgb, stm, sts, stix);
        k_dmerge<<<NCH + 1, NTHR, 0, stream>>>(lgb, stm, sts, stix, emb, out, xn, tt);
    }
}

// Round 4
// 3785.750 us; speedup vs baseline: 1.5287x; 1.5287x over previous
//
#include <hip/hip_runtime.h>
#include <math.h>

#define BB   4
#define SS   64
#define DD   512
#define HH   8
#define DHH  64
#define DFFF 2048
#define LL   2
#define VV   32128
#define TT   16
#define EPSV 1e-6f
#define NEGB (-1e9f)
#define NTHR 256
#define NCH  502             // 502 * 64 = 32128 vocab columns
#define STS  512             // stride for per-chunk stat arrays

#define BSDc ((size_t)131072)    // B*S*D
#define DD2c ((size_t)262144)    // D*D

// ===================== encoder kernels ====================================

__global__ __launch_bounds__(NTHR) void k_embed(const int* __restrict__ ids,
        const float* __restrict__ emb, float* __restrict__ xe, float* __restrict__ xd) {
    int blk = blockIdx.x, tid = threadIdx.x;
    int id = ids[blk];
    const float* src = emb + (size_t)id * DD;
    float* dst = xe + (size_t)blk * DD;
    for (int k = tid; k < DD; k += NTHR) dst[k] = src[k];
    if (blk < BB) {
        float* xdp = xd + (size_t)blk * DD;
        for (int k = tid; k < DD; k += NTHR) xdp[k] = emb[k];   // emb[PAD=0]
    }
}

__global__ __launch_bounds__(NTHR) void k_rms(const float* __restrict__ x,
        const float* __restrict__ ln, float* __restrict__ h) {
    __shared__ float sm[NTHR];
    int row = blockIdx.x, tid = threadIdx.x;
    const float* xr = x + (size_t)row * DD;
    float local = 0.f;
    for (int k = tid; k < DD; k += NTHR) { float v = xr[k]; local += v * v; }
    sm[tid] = local; __syncthreads();
    for (int s = 128; s > 0; s >>= 1) { if (tid < s) sm[tid] += sm[tid + s]; __syncthreads(); }
    float scale = 1.0f / sqrtf(sm[0] / DD + EPSV);
    for (int k = tid; k < DD; k += NTHR) h[(size_t)row * DD + k] = xr[k] * scale * ln[k];
}

// 64x64 GEMM tile; A is [256 x K], W is [K x N]
__device__ __forceinline__ void d_gemm_tile(const float* __restrict__ A, const float* __restrict__ W,
        float* __restrict__ C, const float* __restrict__ res,
        int K, int N, int relu, int tile, float* sm) {
    float* As = sm;                 // [16][65]
    float* Ws = sm + 16 * 65;       // [16][64]
    int tid = threadIdx.x;
    int tr = tid >> 4, tc = tid & 15;
    int nb = N >> 6;
    int row0 = (tile / nb) * 64, col0 = (tile % nb) * 64;
    float acc[4][4] = {};
    for (int k0 = 0; k0 < K; k0 += 16) {
        for (int i = tid; i < 64 * 16; i += NTHR) {
            int r = i >> 4, kk = i & 15;
            As[kk * 65 + r] = A[(size_t)(row0 + r) * K + k0 + kk];
        }
        for (int i = tid; i < 16 * 64; i += NTHR) {
            int kk = i >> 6, c = i & 63;
            Ws[kk * 64 + c] = W[(size_t)(k0 + kk) * N + col0 + c];
        }
        __syncthreads();
        #pragma unroll
        for (int kk = 0; kk < 16; kk++) {
            float a[4], b[4];
            #pragma unroll
            for (int j = 0; j < 4; j++) { a[j] = As[kk * 65 + tr * 4 + j]; b[j] = Ws[kk * 64 + tc * 4 + j]; }
            #pragma unroll
            for (int r = 0; r < 4; r++)
                #pragma unroll
                for (int c = 0; c < 4; c++) acc[r][c] += a[r] * b[c];
        }
        __syncthreads();
    }
    #pragma unroll
    for (int r = 0; r < 4; r++)
        #pragma unroll
        for (int c = 0; c < 4; c++) {
            int gr = row0 + tr * 4 + r, gc = col0 + tc * 4 + c;
            float v = acc[r][c];
            if (res) v += res[(size_t)gr * N + gc];
            if (relu) v = fmaxf(v, 0.f);
            C[(size_t)gr * N + gc] = v;
        }
}

__global__ __launch_bounds__(NTHR) void k_gemm(const float* __restrict__ A, const float* __restrict__ W,
        float* __restrict__ C, const float* __restrict__ res, int K, int N, int relu) {
    __shared__ float sm[16 * 65 + 16 * 64];
    d_gemm_tile(A, W, C, res, K, N, relu, blockIdx.x, sm);
}

__global__ __launch_bounds__(NTHR) void k_qkv(const float* __restrict__ A,
        const float* __restrict__ wq, const float* __restrict__ wk, const float* __restrict__ wv,
        float* __restrict__ qkv) {
    __shared__ float sm[16 * 65 + 16 * 64];
    int m = blockIdx.x >> 5, t2 = blockIdx.x & 31;
    const float* W = (m == 0) ? wq : (m == 1 ? wk : wv);
    d_gemm_tile(A, W, qkv + (size_t)m * BSDc, nullptr, 512, 512, 0, t2, sm);
}

__global__ __launch_bounds__(NTHR) void k_ckcv(const float* __restrict__ A,
        const float* __restrict__ wck, const float* __restrict__ wcv,
        float* __restrict__ cK, float* __restrict__ cV) {
    __shared__ float sm[16 * 65 + 16 * 64];
    int m = blockIdx.x >> 5, t2 = blockIdx.x & 31;
    const float* W = (m < 2) ? (wck + (size_t)m * DD2c) : (wcv + (size_t)(m - 2) * DD2c);
    float* O = (m < 2) ? (cK + (size_t)m * BSDc) : (cV + (size_t)(m - 2) * BSDc);
    d_gemm_tile(A, W, O, nullptr, 512, 512, 0, t2, sm);
}

__global__ __launch_bounds__(NTHR) void k_eattn(const float* __restrict__ qkv,
        const float* __restrict__ mask, float* __restrict__ o) {
    __shared__ float sm[3 * 64 * 65];
    int job = blockIdx.x;
    int b = job / HH, h = job % HH;
    int tid = threadIdx.x;
    int lane = tid & 63, wave = tid >> 6;
    float* qq = sm;
    float* kk = sm + 64 * 65;
    float* vv = sm + 2 * 64 * 65;
    for (int i = tid; i < SS * DHH; i += NTHR) {
        int s = i >> 6, d = i & 63;
        size_t src = (size_t)(b * SS + s) * DD + h * DHH + d;
        qq[s * 65 + d] = qkv[src];
        kk[s * 65 + d] = qkv[BSDc + src];
        vv[s * 65 + d] = qkv[2 * BSDc + src];
    }
    __syncthreads();
    float bias = (1.0f - mask[b * SS + lane]) * NEGB;
    for (int r = 0; r < 16; r++) {
        int s = wave * 16 + r;
        float sc = 0.f;
        for (int i = 0; i < DHH; i++) sc += qq[s * 65 + i] * kk[lane * 65 + i];
        sc = sc * 0.125f + bias;
        float m = sc;
        for (int o2 = 32; o2 > 0; o2 >>= 1) m = fmaxf(m, __shfl_xor(m, o2));
        float e = expf(sc - m);
        float sum = e;
        for (int o2 = 32; o2 > 0; o2 >>= 1) sum += __shfl_xor(sum, o2);
        float p = e / sum;
        float acc = 0.f;
        for (int t2 = 0; t2 < SS; t2++) acc += __shfl(p, t2) * vv[t2 * 65 + lane];
        o[(size_t)(b * SS + s) * DD + h * DHH + lane] = acc;
    }
}

// ===================== decode kernels =====================================

// small-M GEMV: optional RMSNorm(A rows)*ln -> hAT, then cols [cb*NC, +NC) of W
template<int K, int NC>
__device__ __forceinline__ void gemv_dev(const float* __restrict__ A, const float* __restrict__ ln,
        const float* __restrict__ W, float* __restrict__ O, int ostr, int N,
        const float* __restrict__ res, int relu, int cb, float* sm) {
    constexpr int C4N = NC / 4;            // float4 col-threads
    constexpr int KSN = NTHR / C4N;        // k-slices
    constexpr int KC  = K / KSN;           // k per slice
    const int tid = threadIdx.x, lane = tid & 63, wv = tid >> 6;
    float* hAT = sm;                       // K*4
    float* red = sm + K * 4;               // 4096
    float* scl = sm + K * 4 + 4096;        // 4
    if (ln) {
        const float* ar = A + (size_t)wv * K;
        float loc = 0.f;
        for (int k = lane; k < K; k += 64) { float x = ar[k]; loc += x * x; }
        for (int o = 32; o > 0; o >>= 1) loc += __shfl_xor(loc, o);
        if (lane == 0) scl[wv] = 1.0f / sqrtf(loc / K + EPSV);
    }
    __syncthreads();
    float s0 = ln ? scl[0] : 1.f, s1 = ln ? scl[1] : 1.f;
    float s2 = ln ? scl[2] : 1.f, s3 = ln ? scl[3] : 1.f;
    for (int k = tid; k < K; k += NTHR) {
        float lw = ln ? ln[k] : 1.0f;
        float4 h;
        h.x = A[k] * s0 * lw;
        h.y = A[K + k] * s1 * lw;
        h.z = A[2 * K + k] * s2 * lw;
        h.w = A[3 * K + k] * s3 * lw;
        *(float4*)(hAT + (size_t)k * 4) = h;
    }
    __syncthreads();
    const int c4 = tid % C4N, ks = tid / C4N;
    const float4* W4 = (const float4*)W;
    const int col0 = cb * NC;
    float acc[4][4] = {};
    const int kb = ks * KC;
    #pragma unroll 8
    for (int kk = 0; kk < KC; kk++) {
        int k = kb + kk;
        float4 w4 = W4[(size_t)k * (N >> 2) + (col0 >> 2) + c4];
        float4 h4 = *(float4*)(hAT + (size_t)k * 4);
        float hb[4] = {h4.x, h4.y, h4.z, h4.w};
        float wb[4] = {w4.x, w4.y, w4.z, w4.w};
        #pragma unroll
        for (int b = 0; b < 4; b++)
            #pragma unroll
            for (int ci = 0; ci < 4; ci++) acc[b][ci] += hb[b] * wb[ci];
    }
    {
        float* rp = red + (size_t)ks * (NC * 4) + c4 * 4;
        #pragma unroll
        for (int b = 0; b < 4; b++)
            #pragma unroll
            for (int ci = 0; ci < 4; ci++) rp[b * NC + ci] = acc[b][ci];
    }
    __syncthreads();
    for (int o = tid; o < 4 * NC; o += NTHR) {
        int b = o / NC, c = o % NC;
        float v = 0.f;
        #pragma unroll
        for (int k2 = 0; k2 < KSN; k2++) v += red[(size_t)k2 * (NC * 4) + o];
        if (res) v += res[(size_t)b * ostr + col0 + c];
        if (relu) v = fmaxf(v, 0.f);
        O[(size_t)b * ostr + col0 + c] = v;
    }
}

template<int K, int NC>
__global__ __launch_bounds__(NTHR) void k_gemv(const float* __restrict__ A, const float* __restrict__ ln,
        const float* __restrict__ W, float* __restrict__ O, int ostr, int N,
        const float* __restrict__ res, int relu) {
    __shared__ float sm[K * 4 + 4096 + 4];
    gemv_dev<K, NC>(A, ln, W, O, ostr, N, res, relu, blockIdx.x, sm);
}

__global__ __launch_bounds__(NTHR) void k_dqkv(const float* __restrict__ xc, const float* __restrict__ ln1,
        const float* __restrict__ wq, const float* __restrict__ wk, const float* __restrict__ wv,
        float* __restrict__ dq, float* __restrict__ sKw, float* __restrict__ sVw) {
    __shared__ float sm[512 * 4 + 4096 + 4];
    int m = blockIdx.x >> 5, cb = blockIdx.x & 31;
    const float* W = (m == 0) ? wq : (m == 1 ? wk : wv);
    float* O = (m == 0) ? dq : (m == 1 ? sKw : sVw);
    int ostr = (m == 0) ? DD : TT * DD;
    gemv_dev<512, 16>(xc, ln1, W, O, ostr, 512, nullptr, 0, cb, sm);
}

// fused self-attn (1 head per block-pair) + o-proj partial, atomicAdd into xc.
// 16 blocks: h = blk>>1, half = blk&1 -> output cols [half*256, +256)
__global__ __launch_bounds__(NTHR) void k_dselfso(const float* __restrict__ dq,
        const float* __restrict__ sKl, const float* __restrict__ sVl,
        const float* __restrict__ Wso, float* __restrict__ xc, int p) {
    __shared__ float qs[256];      // q[b][64] for this head
    __shared__ float attT[256];    // att[d][b] transposed
    __shared__ float red[4096];    // 4 k-slices x (4b x 256c)
    int blk = blockIdx.x;
    int h = blk >> 1, half = blk & 1;
    int tid = threadIdx.x, lane = tid & 63, b = tid >> 6;
    qs[b * 64 + lane] = dq[(size_t)b * DD + h * DHH + lane];
    __syncthreads();
    float sc = -1e30f;
    if (lane <= p) {
        const float* kr = sKl + ((size_t)b * TT + lane) * DD + h * DHH;
        float s2 = 0.f;
        #pragma unroll 16
        for (int i = 0; i < DHH; i++) s2 += qs[b * 64 + i] * kr[i];
        sc = s2 * 0.125f;
    }
    float m = sc;
    for (int o2 = 32; o2 > 0; o2 >>= 1) m = fmaxf(m, __shfl_xor(m, o2));
    float e = (lane <= p) ? expf(sc - m) : 0.f;
    float sum = e;
    for (int o2 = 32; o2 > 0; o2 >>= 1) sum += __shfl_xor(sum, o2);
    float pr = e / sum;
    float acc = 0.f;
    for (int j = 0; j <= p; j++) {
        float pj = __shfl(pr, j);
        acc += pj * sVl[((size_t)b * TT + j) * DD + h * DHH + lane];
    }
    attT[lane * 4 + b] = acc;
    __syncthreads();
    {   // o-proj partial: out[b][c] = sum_d att[b][d] * Wso[h*64+d][half*256+c]
        int c4 = tid & 63, ks = tid >> 6;
        const float4* W4 = (const float4*)Wso;
        float ac[4][4] = {};
        int db = ks * 16;
        #pragma unroll
        for (int dd = 0; dd < 16; dd++) {
            int d = db + dd;
            float4 w4 = W4[(size_t)(h * DHH + d) * 128 + half * 64 + c4];
            float wb[4] = {w4.x, w4.y, w4.z, w4.w};
            #pragma unroll
            for (int bb = 0; bb < 4; bb++) {
                float av = attT[d * 4 + bb];
                #pragma unroll
                for (int ci = 0; ci < 4; ci++) ac[bb][ci] += av * wb[ci];
            }
        }
        float* rp = red + ks * 1024 + c4 * 4;
        #pragma unroll
        for (int bb = 0; bb < 4; bb++)
            #pragma unroll
            for (int ci = 0; ci < 4; ci++) rp[bb * 256 + ci] = ac[bb][ci];
    }
    __syncthreads();
    for (int o = tid; o < 1024; o += NTHR) {
        int bb = o >> 8, c = o & 255;
        float v = red[o] + red[1024 + o] + red[2048 + o] + red[3072 + o];
        atomicAdd(xc + (size_t)bb * DD + half * 256 + c, v);
    }
}

// fused cross-attn (1 head per block-pair) + o-proj partial, atomicAdd into xc.
__global__ __launch_bounds__(NTHR) void k_dcrossco(const float* __restrict__ dq,
        const float* __restrict__ cKl, const float* __restrict__ cVl,
        const float* __restrict__ mask, const float* __restrict__ Wco,
        float* __restrict__ xc) {
    __shared__ float qs[256];
    __shared__ float prS[256];     // probabilities [b][64 keys]
    __shared__ float attT[256];
    __shared__ float red[4096];
    int blk = blockIdx.x;
    int h = blk >> 1, half = blk & 1;
    int tid = threadIdx.x, lane = tid & 63, b = tid >> 6;
    qs[b * 64 + lane] = dq[(size_t)b * DD + h * DHH + lane];
    __syncthreads();
    const float* kr = cKl + ((size_t)b * SS + lane) * DD + h * DHH;
    float s2 = 0.f;
    #pragma unroll 16
    for (int i = 0; i < DHH; i++) s2 += qs[b * 64 + i] * kr[i];
    float sc = s2 * 0.125f + (1.0f - mask[b * SS + lane]) * NEGB;
    float m = sc;
    for (int o2 = 32; o2 > 0; o2 >>= 1) m = fmaxf(m, __shfl_xor(m, o2));
    float e = expf(sc - m);
    float sum = e;
    for (int o2 = 32; o2 > 0; o2 >>= 1) sum += __shfl_xor(sum, o2);
    prS[b * 64 + lane] = e / sum;
    // V accumulate: LDS-prob + 4 independent accumulators (pipelined loads)
    const float* vbase = cVl + (size_t)b * SS * DD + h * DHH + lane;
    float a0 = 0.f, a1 = 0.f, a2 = 0.f, a3 = 0.f;
    #pragma unroll 4
    for (int j = 0; j < SS; j += 4) {
        a0 += prS[b * 64 + j]     * vbase[(size_t)j * DD];
        a1 += prS[b * 64 + j + 1] * vbase[(size_t)(j + 1) * DD];
        a2 += prS[b * 64 + j + 2] * vbase[(size_t)(j + 2) * DD];
        a3 += prS[b * 64 + j + 3] * vbase[(size_t)(j + 3) * DD];
    }
    attT[lane * 4 + b] = (a0 + a1) + (a2 + a3);
    __syncthreads();
    {   // o-proj partial
        int c4 = tid & 63, ks = tid >> 6;
        const float4* W4 = (const float4*)Wco;
        float ac[4][4] = {};
        int db = ks * 16;
        #pragma unroll
        for (int dd = 0; dd < 16; dd++) {
            int d = db + dd;
            float4 w4 = W4[(size_t)(h * DHH + d) * 128 + half * 64 + c4];
            float wb[4] = {w4.x, w4.y, w4.z, w4.w};
            #pragma unroll
            for (int bb = 0; bb < 4; bb++) {
                float av = attT[d * 4 + bb];
                #pragma unroll
                for (int ci = 0; ci < 4; ci++) ac[bb][ci] += av * wb[ci];
            }
        }
        float* rp = red + ks * 1024 + c4 * 4;
        #pragma unroll
        for (int bb = 0; bb < 4; bb++)
            #pragma unroll
            for (int ci = 0; ci < 4; ci++) rp[bb * 256 + ci] = ac[bb][ci];
    }
    __syncthreads();
    for (int o = tid; o < 1024; o += NTHR) {
        int bb = o >> 8, c = o & 255;
        float v = red[o] + red[1024 + o] + red[2048 + o] + red[3072 + o];
        atomicAdd(xc + (size_t)bb * DD + half * 256 + c, v);
    }
}

// lm_head chunk (blocks 0..501) + stats; block 502 zeroes next-state
__global__ __launch_bounds__(NTHR) void k_lmhead(const float* __restrict__ xc, float* __restrict__ xn,
        const float* __restrict__ lnf, const float* __restrict__ Wlm,
        float* __restrict__ lgb, float* __restrict__ stm, float* __restrict__ sts,
        int* __restrict__ stix) {
    int blk = blockIdx.x, tid = threadIdx.x, lane = tid & 63, wave = tid >> 6;
    if (blk >= NCH) {
        for (int k = tid; k < BB * DD; k += NTHR) xn[k] = 0.f;
        return;
    }
    __shared__ float hAT[2048];
    __shared__ float red[4096];
    __shared__ float msc[4];
    __shared__ float lgl[256];
    for (int k = tid; k < DD; k += NTHR) {
        float4 r;
        r.x = xc[k];          r.y = xc[DD + k];
        r.z = xc[2 * DD + k]; r.w = xc[3 * DD + k];
        *(float4*)(hAT + (size_t)k * 4) = r;
    }
    __syncthreads();
    {
        float loc = 0.f;
        for (int k = lane; k < DD; k += 64) { float x = hAT[k * 4 + wave]; loc += x * x; }
        for (int o = 32; o > 0; o >>= 1) loc += __shfl_xor(loc, o);
        if (lane == 0) msc[wave] = 1.0f / sqrtf(loc / DD + EPSV);
    }
    __syncthreads();
    float s0 = msc[0], s1 = msc[1], s2 = msc[2], s3 = msc[3];
    for (int k = tid; k < DD; k += NTHR) {
        float lw = lnf[k];
        float4 r = *(float4*)(hAT + (size_t)k * 4);
        r.x *= s0 * lw; r.y *= s1 * lw; r.z *= s2 * lw; r.w *= s3 * lw;
        *(float4*)(hAT + (size_t)k * 4) = r;
    }
    __syncthreads();
    {   // 64 cols, 16 c4-threads x 16 k-slices of 32
        int c4 = tid & 15, ks = tid >> 4;
        const float4* W4 = (const float4*)Wlm;
        float acc[4][4] = {};
        int kb = ks * 32;
        #pragma unroll
        for (int kk = 0; kk < 32; kk++) {
            int k = kb + kk;
            float4 w4 = W4[(size_t)k * (VV >> 2) + blk * 16 + c4];
            float4 h4 = *(float4*)(hAT + (size_t)k * 4);
            float hb[4] = {h4.x, h4.y, h4.z, h4.w};
            float wb[4] = {w4.x, w4.y, w4.z, w4.w};
            #pragma unroll
            for (int b = 0; b < 4; b++)
                #pragma unroll
                for (int ci = 0; ci < 4; ci++) acc[b][ci] += hb[b] * wb[ci];
        }
        float* rp = red + ks * 256 + c4 * 4;
        #pragma unroll
        for (int b = 0; b < 4; b++)
            #pragma unroll
            for (int ci = 0; ci < 4; ci++) rp[b * 64 + ci] = acc[b][ci];
    }
    __syncthreads();
    {
        float v = 0.f;
        #pragma unroll
        for (int k2 = 0; k2 < 16; k2++) v += red[k2 * 256 + tid];
        lgl[tid] = v;
        lgb[(size_t)(tid >> 6) * VV + blk * 64 + (tid & 63)] = v;
    }
    __syncthreads();
    {
        int b = wave;
        float v0 = lgl[b * 64 + lane];
        float mx = v0; int ix = lane;
        for (int o = 32; o > 0; o >>= 1) {
            float om = __shfl_xor(mx, o); int oi = __shfl_xor(ix, o);
            if (om > mx || (om == mx && oi < ix)) { mx = om; ix = oi; }
        }
        float s = expf(v0 - mx);
        for (int o = 32; o > 0; o >>= 1) s += __shfl_xor(s, o);
        if (lane == 0) {
            stm[b * STS + blk] = mx;
            sts[b * STS + blk] = s;
            stix[b * STS + blk] = blk * 64 + ix;
        }
    }
}

// merge stats + probs out + soft-emb partial -> xn; block 502 writes preds
__global__ __launch_bounds__(NTHR) void k_dmerge(const float* __restrict__ lgb,
        const float* __restrict__ stm, const float* __restrict__ sts, const int* __restrict__ stix,
        const float* __restrict__ emb, float* __restrict__ out, float* __restrict__ xn, int tt) {
    __shared__ float mM[8];
    __shared__ int jS[4];
    __shared__ float pT[256];
    __shared__ float red[4096];
    int blk = blockIdx.x, tid = threadIdx.x, lane = tid & 63, wave = tid >> 6;
    {   // merge per b (wave b)
        int b = wave;
        float M = -1e30f, S = 0.f; int jb = 0;
        for (int j = lane; j < NCH; j += 64) {
            float mj = stm[b * STS + j], sj = sts[b * STS + j];
            if (mj > M) { S = S * expf(M - mj) + sj; M = mj; jb = j; }
            else        { S += sj * expf(mj - M); }
        }
        for (int o = 32; o > 0; o >>= 1) {
            float Mo = __shfl_xor(M, o), So = __shfl_xor(S, o);
            int jo = __shfl_xor(jb, o);
            if (Mo > M || (Mo == M && jo < jb)) { S = S * expf(M - Mo) + So; M = Mo; jb = jo; }
            else { S += So * expf(Mo - M); }
        }
        if (lane == 0) { mM[b] = M; mM[4 + b] = S; jS[b] = jb; }
    }
    __syncthreads();
    if (blk < NCH) {
        {   // final probs for this chunk: write out + stash transposed
            int b = tid >> 6, c = tid & 63;
            float lg = lgb[(size_t)b * VV + blk * 64 + c];
            float p = expf(lg - mM[b]) / mM[4 + b];
            out[((size_t)b * TT + tt) * VV + blk * 64 + c] = p;
            pT[c * 4 + b] = p;
        }
        __syncthreads();
        {   // emb chunk (same 64 vocab rows as this block's logits)
            int c4 = tid & 127, rs = tid >> 7;
            const float4* E4 = (const float4*)emb;
            float4 a0 = {0,0,0,0}, a1 = a0, a2 = a0, a3 = a0;
            int rb = rs * 32;
            #pragma unroll 8
            for (int r = 0; r < 32; r++) {
                int row = rb + r;
                float4 e4 = E4[((size_t)(blk * 64 + row)) * 128 + c4];
                float4 p4 = *(float4*)(pT + row * 4);
                a0.x += p4.x * e4.x; a0.y += p4.x * e4.y; a0.z += p4.x * e4.z; a0.w += p4.x * e4.w;
                a1.x += p4.y * e4.x; a1.y += p4.y * e4.y; a1.z += p4.y * e4.z; a1.w += p4.y * e4.w;
                a2.x += p4.z * e4.x; a2.y += p4.z * e4.y; a2.z += p4.z * e4.z; a2.w += p4.z * e4.w;
                a3.x += p4.w * e4.x; a3.y += p4.w * e4.y; a3.z += p4.w * e4.z; a3.w += p4.w * e4.w;
            }
            float* rp = red + rs * 2048 + c4 * 4;
            rp[0]        = a0.x; rp[1]        = a0.y; rp[2]        = a0.z; rp[3]        = a0.w;
            rp[512 + 0]  = a1.x; rp[512 + 1]  = a1.y; rp[512 + 2]  = a1.z; rp[512 + 3]  = a1.w;
            rp[1024 + 0] = a2.x; rp[1024 + 1] = a2.y; rp[1024 + 2] = a2.z; rp[1024 + 3] = a2.w;
            rp[1536 + 0] = a3.x; rp[1536 + 1] = a3.y; rp[1536 + 2] = a3.z; rp[1536 + 3] = a3.w;
        }
        __syncthreads();
        #pragma unroll
        for (int i = 0; i < 8; i++) {
            int o = tid + i * 256;
            atomicAdd(xn + o, red[o] + red[2048 + o]);
        }
    } else {
        if (tid < 4) {   // pred flags
            int col = stix[tid * STS + jS[tid]];
            out[(size_t)BB * TT * VV + tid * TT + tt] = (col == 0) ? 1.0f : 0.0f;
        }
    }
}

// ===================== launch =============================================
extern "C" void kernel_launch(void* const* d_in, const int* in_sizes, int n_in,
                              void* d_out, int out_size, void* d_ws, size_t ws_size,
                              hipStream_t stream) {
    const int*   ids     = (const int*)  d_in[0];
    const float* mask    = (const float*)d_in[1];
    const float* emb     = (const float*)d_in[2];
    const float* enc_wq  = (const float*)d_in[3];
    const float* enc_wk  = (const float*)d_in[4];
    const float* enc_wv  = (const float*)d_in[5];
    const float* enc_wo  = (const float*)d_in[6];
    const float* enc_ln1 = (const float*)d_in[7];
    const float* enc_w1  = (const float*)d_in[8];
    const float* enc_w2  = (const float*)d_in[9];
    const float* enc_ln2 = (const float*)d_in[10];
    const float* enc_lnf = (const float*)d_in[11];
    const float* dec_sq  = (const float*)d_in[12];
    const float* dec_sk  = (const float*)d_in[13];
    const float* dec_sv  = (const float*)d_in[14];
    const float* dec_so  = (const float*)d_in[15];
    const float* dec_ln1 = (const float*)d_in[16];
    const float* dec_cq  = (const float*)d_in[17];
    const float* dec_ck  = (const float*)d_in[18];
    const float* dec_cv  = (const float*)d_in[19];
    const float* dec_co  = (const float*)d_in[20];
    const float* dec_ln2 = (const float*)d_in[21];
    const float* dec_w1  = (const float*)d_in[22];
    const float* dec_w2  = (const float*)d_in[23];
    const float* dec_ln3 = (const float*)d_in[24];
    const float* dec_lnf = (const float*)d_in[25];
    const float* lm_head = (const float*)d_in[26];
    float* out = (float*)d_out;

    // ---- workspace layout (floats) ----
    float* ws    = (float*)d_ws;
    float* xe    = ws;                                  // 131072
    float* qkv   = xe + BSDc;                           // 393216
    float* hbuf  = qkv + 3 * BSDc;                      // 131072
    float* attb  = hbuf + BSDc;                         // 131072
    float* ffbuf = attb + BSDc;                         // 524288
    float* cK    = ffbuf + (size_t)BB * SS * DFFF;      // 262144
    float* cV    = cK + LL * BSDc;                      // 262144
    float* sK    = cV + LL * BSDc;                      // 65536
    float* sV    = sK + (size_t)LL * BB * TT * DD;      // 65536
    float* xdA   = sV + (size_t)LL * BB * TT * DD;      // 2048
    float* xdB   = xdA + 2048;                          // 2048
    float* dq    = xdB + 2048;                          // 2048
    float* dff   = dq + 2048;                           // 8192
    float* stm   = dff + 8192;                          // 2048
    float* sts   = stm + 4 * STS;                       // 2048
    int*   stix  = (int*)(sts + 4 * STS);               // 2048
    float* lgb   = (float*)(stix) + 2048;               // 128512 (4*VV)

    // ---------- encoder ----------
    k_embed<<<256, NTHR, 0, stream>>>(ids, emb, xe, xdA);
    for (int l = 0; l < LL; l++) {
        k_rms<<<256, NTHR, 0, stream>>>(xe, enc_ln1 + (size_t)l * DD, hbuf);
        k_qkv<<<96, NTHR, 0, stream>>>(hbuf, enc_wq + (size_t)l * DD2c,
                                       enc_wk + (size_t)l * DD2c, enc_wv + (size_t)l * DD2c, qkv);
        k_eattn<<<32, NTHR, 0, stream>>>(qkv, mask, attb);
        k_gemm<<<32, NTHR, 0, stream>>>(attb, enc_wo + (size_t)l * DD2c, xe, xe, 512, 512, 0);
        k_rms<<<256, NTHR, 0, stream>>>(xe, enc_ln2 + (size_t)l * DD, hbuf);
        k_gemm<<<128, NTHR, 0, stream>>>(hbuf, enc_w1 + (size_t)l * DD * DFFF, ffbuf, nullptr, 512, 2048, 1);
        k_gemm<<<32, NTHR, 0, stream>>>(ffbuf, enc_w2 + (size_t)l * DFFF * DD, xe, xe, 2048, 512, 0);
    }
    k_rms<<<256, NTHR, 0, stream>>>(xe, enc_lnf, hbuf);
    k_ckcv<<<128, NTHR, 0, stream>>>(hbuf, dec_ck, dec_cv, cK, cV);

    // ---------- decode ----------
    for (int tt = 0; tt < TT; tt++) {
        float* xc = (tt & 1) ? xdB : xdA;
        float* xn = (tt & 1) ? xdA : xdB;
        for (int l = 0; l < LL; l++) {
            k_dqkv<<<96, NTHR, 0, stream>>>(xc, dec_ln1 + (size_t)l * DD,
                    dec_sq + (size_t)l * DD2c, dec_sk + (size_t)l * DD2c, dec_sv + (size_t)l * DD2c,
                    dq, sK + ((size_t)l * BB * TT + tt) * DD, sV + ((size_t)l * BB * TT + tt) * DD);
            k_dselfso<<<16, NTHR, 0, stream>>>(dq, sK + (size_t)l * BB * TT * DD,
                    sV + (size_t)l * BB * TT * DD, dec_so + (size_t)l * DD2c, xc, tt);
            k_gemv<512, 16><<<32, NTHR, 0, stream>>>(xc, dec_ln2 + (size_t)l * DD,
                    dec_cq + (size_t)l * DD2c, dq, DD, 512, nullptr, 0);
            k_dcrossco<<<16, NTHR, 0, stream>>>(dq, cK + (size_t)l * BSDc, cV + (size_t)l * BSDc,
                    mask, dec_co + (size_t)l * DD2c, xc);
            k_gemv<512, 16><<<128, NTHR, 0, stream>>>(xc, dec_ln3 + (size_t)l * DD,
                    dec_w1 + (size_t)l * DD * DFFF, dff, DFFF, DFFF, nullptr, 1);
            k_gemv<2048, 8><<<64, NTHR, 0, stream>>>(dff, nullptr, dec_w2 + (size_t)l * DFFF * DD,
                    xc, DD, 512, xc, 0);
        }
        k_lmhead<<<NCH + 1, NTHR, 0, stream>>>(xc, xn, dec_lnf, lm_head, lgb, stm, sts, stix);
        k_dmerge<<<NCH + 1, NTHR, 0, stream>>>(lgb, stm, sts, stix, emb, out, xn, tt);
    }
}

// Round 5
// 3774.874 us; speedup vs baseline: 1.5331x; 1.0029x over previous
//
#include <hip/hip_runtime.h>
#include <math.h>

#define BB   4
#define SS   64
#define DD   512
#define HH   8
#define DHH  64
#define DFFF 2048
#define LL   2
#define VV   32128
#define TT   16
#define EPSV 1e-6f
#define NEGB (-1e9f)
#define NTHR 256
#define NCH  502             // 502 * 64 = 32128 vocab columns
#define STS  512             // stride for per-chunk stat arrays

#define BSDc ((size_t)131072)    // B*S*D
#define DD2c ((size_t)262144)    // D*D

// ===================== encoder kernels ====================================

__global__ __launch_bounds__(NTHR) void k_embed(const int* __restrict__ ids,
        const float* __restrict__ emb, float* __restrict__ xe, float* __restrict__ xd,
        float* __restrict__ accb) {
    int blk = blockIdx.x, tid = threadIdx.x;
    int id = ids[blk];
    const float* src = emb + (size_t)id * DD;
    float* dst = xe + (size_t)blk * DD;
    for (int k = tid; k < DD; k += NTHR) dst[k] = src[k];
    if (blk < BB) {
        float* xdp = xd + (size_t)blk * DD;
        for (int k = tid; k < DD; k += NTHR) xdp[k] = emb[k];   // emb[PAD=0]
    }
    if (blk == 4) {
        for (int k = tid; k < 2 * LL * 2048; k += NTHR) accb[k] = 0.f;
    }
}

// 64x64 GEMM tile; A is [256 x K], W is [K x N]
__device__ __forceinline__ void d_gemm_tile(const float* __restrict__ A, const float* __restrict__ W,
        float* __restrict__ C, const float* __restrict__ res,
        int K, int N, int relu, int tile, float* sm) {
    float* As = sm;                 // [16][65]
    float* Ws = sm + 16 * 65;       // [16][64]
    int tid = threadIdx.x;
    int tr = tid >> 4, tc = tid & 15;
    int nb = N >> 6;
    int row0 = (tile / nb) * 64, col0 = (tile % nb) * 64;
    float acc[4][4] = {};
    for (int k0 = 0; k0 < K; k0 += 16) {
        for (int i = tid; i < 64 * 16; i += NTHR) {
            int r = i >> 4, kk = i & 15;
            As[kk * 65 + r] = A[(size_t)(row0 + r) * K + k0 + kk];
        }
        for (int i = tid; i < 16 * 64; i += NTHR) {
            int kk = i >> 6, c = i & 63;
            Ws[kk * 64 + c] = W[(size_t)(k0 + kk) * N + col0 + c];
        }
        __syncthreads();
        #pragma unroll
        for (int kk = 0; kk < 16; kk++) {
            float a[4], b[4];
            #pragma unroll
            for (int j = 0; j < 4; j++) { a[j] = As[kk * 65 + tr * 4 + j]; b[j] = Ws[kk * 64 + tc * 4 + j]; }
            #pragma unroll
            for (int r = 0; r < 4; r++)
                #pragma unroll
                for (int c = 0; c < 4; c++) acc[r][c] += a[r] * b[c];
        }
        __syncthreads();
    }
    #pragma unroll
    for (int r = 0; r < 4; r++)
        #pragma unroll
        for (int c = 0; c < 4; c++) {
            int gr = row0 + tr * 4 + r, gc = col0 + tc * 4 + c;
            float v = acc[r][c];
            if (res) v += res[(size_t)gr * N + gc];
            if (relu) v = fmaxf(v, 0.f);
            C[(size_t)gr * N + gc] = v;
        }
}

// same, but A is raw x: per-row RMS scale; ln folded into W rows. K=512.
__device__ __forceinline__ void d_gemm_rms(const float* __restrict__ A, const float* __restrict__ lnw,
        const float* __restrict__ W, float* __restrict__ C, const float* __restrict__ res,
        int N, int relu, int tile, float* sm) {
    float* As  = sm;                 // [16][65]
    float* Ws  = sm + 16 * 65;       // [16][64]
    float* ps  = sm + 2064;          // 256 partials
    float* scl = sm + 2320;          // 64 row scales
    int tid = threadIdx.x;
    int tr = tid >> 4, tc = tid & 15;
    int nb = N >> 6;
    int row0 = (tile / nb) * 64, col0 = (tile % nb) * 64;
    {   // row RMS scales: 4 threads per row
        int r = tid >> 2, p = tid & 3;
        const float4* xr = (const float4*)(A + (size_t)(row0 + r) * 512 + p * 128);
        float s = 0.f;
        #pragma unroll
        for (int i = 0; i < 32; i++) { float4 v = xr[i]; s += v.x*v.x + v.y*v.y + v.z*v.z + v.w*v.w; }
        ps[tid] = s;
    }
    __syncthreads();
    if (tid < 64) {
        float s = ps[tid * 4] + ps[tid * 4 + 1] + ps[tid * 4 + 2] + ps[tid * 4 + 3];
        scl[tid] = 1.0f / sqrtf(s / 512.f + EPSV);
    }
    __syncthreads();
    float acc[4][4] = {};
    for (int k0 = 0; k0 < 512; k0 += 16) {
        for (int i = tid; i < 64 * 16; i += NTHR) {
            int r = i >> 4, kk = i & 15;
            As[kk * 65 + r] = A[(size_t)(row0 + r) * 512 + k0 + kk] * scl[r];
        }
        for (int i = tid; i < 16 * 64; i += NTHR) {
            int kk = i >> 6, c = i & 63;
            Ws[kk * 64 + c] = W[(size_t)(k0 + kk) * N + col0 + c] * lnw[k0 + kk];
        }
        __syncthreads();
        #pragma unroll
        for (int kk = 0; kk < 16; kk++) {
            float a[4], b[4];
            #pragma unroll
            for (int j = 0; j < 4; j++) { a[j] = As[kk * 65 + tr * 4 + j]; b[j] = Ws[kk * 64 + tc * 4 + j]; }
            #pragma unroll
            for (int r = 0; r < 4; r++)
                #pragma unroll
                for (int c = 0; c < 4; c++) acc[r][c] += a[r] * b[c];
        }
        __syncthreads();
    }
    #pragma unroll
    for (int r = 0; r < 4; r++)
        #pragma unroll
        for (int c = 0; c < 4; c++) {
            int gr = row0 + tr * 4 + r, gc = col0 + tc * 4 + c;
            float v = acc[r][c];
            if (res) v += res[(size_t)gr * N + gc];
            if (relu) v = fmaxf(v, 0.f);
            C[(size_t)gr * N + gc] = v;
        }
}

__global__ __launch_bounds__(NTHR) void k_gemm(const float* __restrict__ A, const float* __restrict__ W,
        float* __restrict__ C, const float* __restrict__ res, int K, int N, int relu) {
    __shared__ float sm[16 * 65 + 16 * 64];
    d_gemm_tile(A, W, C, res, K, N, relu, blockIdx.x, sm);
}

__global__ __launch_bounds__(NTHR) void k_gemm_rms(const float* __restrict__ A, const float* __restrict__ lnw,
        const float* __restrict__ W, float* __restrict__ C, const float* __restrict__ res,
        int N, int relu) {
    __shared__ float sm[2384];
    d_gemm_rms(A, lnw, W, C, res, N, relu, blockIdx.x, sm);
}

__global__ __launch_bounds__(NTHR) void k_qkv_f(const float* __restrict__ A, const float* __restrict__ lnw,
        const float* __restrict__ wq, const float* __restrict__ wk, const float* __restrict__ wv,
        float* __restrict__ qkv) {
    __shared__ float sm[2384];
    int m = blockIdx.x >> 5, t2 = blockIdx.x & 31;
    const float* W = (m == 0) ? wq : (m == 1 ? wk : wv);
    d_gemm_rms(A, lnw, W, qkv + (size_t)m * BSDc, nullptr, 512, 0, t2, sm);
}

__global__ __launch_bounds__(NTHR) void k_ckcv_f(const float* __restrict__ A, const float* __restrict__ lnw,
        const float* __restrict__ wck, const float* __restrict__ wcv,
        float* __restrict__ cK, float* __restrict__ cV) {
    __shared__ float sm[2384];
    int m = blockIdx.x >> 5, t2 = blockIdx.x & 31;
    const float* W = (m < 2) ? (wck + (size_t)m * DD2c) : (wcv + (size_t)(m - 2) * DD2c);
    float* O = (m < 2) ? (cK + (size_t)m * BSDc) : (cV + (size_t)(m - 2) * BSDc);
    d_gemm_rms(A, lnw, W, O, nullptr, 512, 0, t2, sm);
}

__global__ __launch_bounds__(NTHR) void k_eattn(const float* __restrict__ qkv,
        const float* __restrict__ mask, float* __restrict__ o) {
    __shared__ float sm[3 * 64 * 65];
    int job = blockIdx.x;
    int b = job / HH, h = job % HH;
    int tid = threadIdx.x;
    int lane = tid & 63, wave = tid >> 6;
    float* qq = sm;
    float* kk = sm + 64 * 65;
    float* vv = sm + 2 * 64 * 65;
    for (int i = tid; i < SS * DHH; i += NTHR) {
        int s = i >> 6, d = i & 63;
        size_t src = (size_t)(b * SS + s) * DD + h * DHH + d;
        qq[s * 65 + d] = qkv[src];
        kk[s * 65 + d] = qkv[BSDc + src];
        vv[s * 65 + d] = qkv[2 * BSDc + src];
    }
    __syncthreads();
    float bias = (1.0f - mask[b * SS + lane]) * NEGB;
    for (int r = 0; r < 16; r++) {
        int s = wave * 16 + r;
        float sc = 0.f;
        for (int i = 0; i < DHH; i++) sc += qq[s * 65 + i] * kk[lane * 65 + i];
        sc = sc * 0.125f + bias;
        float m = sc;
        for (int o2 = 32; o2 > 0; o2 >>= 1) m = fmaxf(m, __shfl_xor(m, o2));
        float e = expf(sc - m);
        float sum = e;
        for (int o2 = 32; o2 > 0; o2 >>= 1) sum += __shfl_xor(sum, o2);
        float p = e / sum;
        float acc = 0.f;
        for (int t2 = 0; t2 < SS; t2++) acc += __shfl(p, t2) * vv[t2 * 65 + lane];
        o[(size_t)(b * SS + s) * DD + h * DHH + lane] = acc;
    }
}

// ===================== decode building blocks =============================

// fold A (+a1 +a2) into hAT[k][b], then RMSNorm*ln in place (single global pass)
__device__ __forceinline__ void build_hAT(const float* __restrict__ A, const float* __restrict__ a1,
        const float* __restrict__ a2, const float* __restrict__ ln, float* hAT, float* scl) {
    const int tid = threadIdx.x, lane = tid & 63, wv = tid >> 6;
    for (int k = tid; k < DD; k += NTHR) {
        float4 h;
        h.x = A[k]; h.y = A[DD + k]; h.z = A[2 * DD + k]; h.w = A[3 * DD + k];
        if (a1) { h.x += a1[k]; h.y += a1[DD + k]; h.z += a1[2 * DD + k]; h.w += a1[3 * DD + k]; }
        if (a2) { h.x += a2[k]; h.y += a2[DD + k]; h.z += a2[2 * DD + k]; h.w += a2[3 * DD + k]; }
        *(float4*)(hAT + (size_t)k * 4) = h;
    }
    __syncthreads();
    float loc = 0.f;
    for (int k = lane; k < DD; k += 64) { float x = hAT[k * 4 + wv]; loc += x * x; }
    for (int o = 32; o > 0; o >>= 1) loc += __shfl_xor(loc, o);
    if (lane == 0) scl[wv] = 1.0f / sqrtf(loc / DD + EPSV);
    __syncthreads();
    float s0 = scl[0], s1 = scl[1], s2 = scl[2], s3 = scl[3];
    for (int k = tid; k < DD; k += NTHR) {
        float lw = ln[k];
        float4 h = *(float4*)(hAT + (size_t)k * 4);
        h.x *= s0 * lw; h.y *= s1 * lw; h.z *= s2 * lw; h.w *= s3 * lw;
        *(float4*)(hAT + (size_t)k * 4) = h;
    }
    __syncthreads();
}

// GEMV on LDS hAT[K][4]: cols [col0, col0+NC) of W[K][N] -> outL[b*NC+c] (LDS)
template<int K, int NC>
__device__ __forceinline__ void gemv_core(const float* hAT, const float* __restrict__ W,
        int N, int col0, float* red, float* outL) {
    constexpr int C4N = NC / 4;
    constexpr int KSN = NTHR / C4N;
    constexpr int KC  = K / KSN;
    const int tid = threadIdx.x;
    const int c4 = tid % C4N, ks = tid / C4N;
    const float4* W4 = (const float4*)W;
    float acc[4][4] = {};
    const int kb = ks * KC;
    #pragma unroll 8
    for (int kk = 0; kk < KC; kk++) {
        int k = kb + kk;
        float4 w4 = W4[(size_t)k * (N >> 2) + (col0 >> 2) + c4];
        float4 h4 = *(const float4*)(hAT + (size_t)k * 4);
        float hb[4] = {h4.x, h4.y, h4.z, h4.w};
        float wb[4] = {w4.x, w4.y, w4.z, w4.w};
        #pragma unroll
        for (int b = 0; b < 4; b++)
            #pragma unroll
            for (int ci = 0; ci < 4; ci++) acc[b][ci] += hb[b] * wb[ci];
    }
    {
        float* rp = red + (size_t)ks * (NC * 4) + c4 * 4;
        #pragma unroll
        for (int b = 0; b < 4; b++)
            #pragma unroll
            for (int ci = 0; ci < 4; ci++) rp[b * NC + ci] = acc[b][ci];
    }
    __syncthreads();
    for (int o = tid; o < 4 * NC; o += NTHR) {
        float v = 0.f;
        #pragma unroll
        for (int k2 = 0; k2 < KSN; k2++) v += red[(size_t)k2 * (NC * 4) + o];
        outL[o] = v;
    }
    __syncthreads();
}

// per-head o-projection partial: accD[b][0..511] += att[d][b] * Wo[h*64+d][n]
__device__ __forceinline__ void oproj_add(const float* attT, const float* __restrict__ Wo,
        int h, float* accD, float* red) {
    const int tid = threadIdx.x;
    const int c4 = tid & 127, ks = tid >> 7;    // 128 float4-cols x 2 d-slices
    const float4* W4 = (const float4*)Wo;
    float ac[4][4] = {};
    const int db = ks * 32;
    #pragma unroll 8
    for (int dd = 0; dd < 32; dd++) {
        int d = db + dd;
        float4 w4 = W4[(size_t)(h * DHH + d) * 128 + c4];
        float wb[4] = {w4.x, w4.y, w4.z, w4.w};
        #pragma unroll
        for (int bb = 0; bb < 4; bb++) {
            float av = attT[d * 4 + bb];
            #pragma unroll
            for (int ci = 0; ci < 4; ci++) ac[bb][ci] += av * wb[ci];
        }
    }
    {
        float* rp = red + ks * 2048 + c4 * 4;
        #pragma unroll
        for (int bb = 0; bb < 4; bb++)
            #pragma unroll
            for (int ci = 0; ci < 4; ci++) rp[bb * 512 + ci] = ac[bb][ci];
    }
    __syncthreads();
    for (int o = tid; o < 2048; o += NTHR) {
        atomicAdd(accD + o, red[o] + red[2048 + o]);   // accD is [4][512] contiguous
    }
}

// fused self block (one head per block): RMS -> q/k/v -> KV publish -> attn -> oproj
__global__ __launch_bounds__(NTHR) void k_self(const float* __restrict__ xc,
        const float* __restrict__ ln1, const float* __restrict__ Wq,
        const float* __restrict__ Wk, const float* __restrict__ Wv,
        const float* __restrict__ Wso, float* __restrict__ sKl, float* __restrict__ sVl,
        float* __restrict__ aS, int tt) {
    __shared__ float hAT[2048];
    __shared__ float red[4096];
    __shared__ float scl[4];
    __shared__ float qh[256];
    __shared__ float kh[256];
    __shared__ float vh[256];
    __shared__ float attT[256];
    const int h = blockIdx.x;
    const int tid = threadIdx.x, lane = tid & 63, b = tid >> 6;

    build_hAT(xc, nullptr, nullptr, ln1, hAT, scl);
    gemv_core<512, 64>(hAT, Wq, 512, h * 64, red, qh);
    gemv_core<512, 64>(hAT, Wk, 512, h * 64, red, kh);
    gemv_core<512, 64>(hAT, Wv, 512, h * 64, red, vh);
    {   // KV publish (this head's slice, current position)
        int c = tid & 63;
        size_t dst = ((size_t)b * TT + tt) * DD + h * DHH + c;
        sKl[dst] = kh[tid];
        sVl[dst] = vh[tid];
    }
    // attention: wave = batch, lane = key position / d index
    float sc = -1e30f;
    if (lane <= tt) {
        float s2 = 0.f;
        if (lane == tt) {
            #pragma unroll 16
            for (int i = 0; i < DHH; i++) s2 += qh[b * 64 + i] * kh[b * 64 + i];
        } else {
            const float* kr = sKl + ((size_t)b * TT + lane) * DD + h * DHH;
            #pragma unroll 16
            for (int i = 0; i < DHH; i++) s2 += qh[b * 64 + i] * kr[i];
        }
        sc = s2 * 0.125f;
    }
    float m = sc;
    for (int o2 = 32; o2 > 0; o2 >>= 1) m = fmaxf(m, __shfl_xor(m, o2));
    float e = (lane <= tt) ? expf(sc - m) : 0.f;
    float sum = e;
    for (int o2 = 32; o2 > 0; o2 >>= 1) sum += __shfl_xor(sum, o2);
    float pr = e / sum;
    float acc = 0.f;
    for (int j = 0; j < tt; j++) {
        float pj = __shfl(pr, j);
        acc += pj * sVl[((size_t)b * TT + j) * DD + h * DHH + lane];
    }
    acc += __shfl(pr, tt) * vh[b * 64 + lane];
    attT[lane * 4 + b] = acc;
    __syncthreads();
    oproj_add(attT, Wso, h, aS, red);
}

// fused cross block (one head per block): RMS(xc+accS) -> q -> attn(cK,cV) -> oproj
__global__ __launch_bounds__(NTHR) void k_cross(const float* __restrict__ xc,
        const float* __restrict__ aS, const float* __restrict__ ln2,
        const float* __restrict__ Wcq, const float* __restrict__ Wco,
        const float* __restrict__ cKl, const float* __restrict__ cVl,
        const float* __restrict__ mask, float* __restrict__ aC) {
    __shared__ float hAT[2048];
    __shared__ float red[4096];
    __shared__ float scl[4];
    __shared__ float qh[256];
    __shared__ float prS[256];
    __shared__ float attT[256];
    const int h = blockIdx.x;
    const int tid = threadIdx.x, lane = tid & 63, b = tid >> 6;

    build_hAT(xc, aS, nullptr, ln2, hAT, scl);
    gemv_core<512, 64>(hAT, Wcq, 512, h * 64, red, qh);
    // attention over encoder K/V (immutable, cached)
    const float* kr = cKl + ((size_t)b * SS + lane) * DD + h * DHH;
    float s2 = 0.f;
    #pragma unroll 16
    for (int i = 0; i < DHH; i++) s2 += qh[b * 64 + i] * kr[i];
    float sc = s2 * 0.125f + (1.0f - mask[b * SS + lane]) * NEGB;
    float m = sc;
    for (int o2 = 32; o2 > 0; o2 >>= 1) m = fmaxf(m, __shfl_xor(m, o2));
    float e = expf(sc - m);
    float sum = e;
    for (int o2 = 32; o2 > 0; o2 >>= 1) sum += __shfl_xor(sum, o2);
    prS[b * 64 + lane] = e / sum;
    const float* vbase = cVl + (size_t)b * SS * DD + h * DHH + lane;
    float a0 = 0.f, a1 = 0.f, a2 = 0.f, a3 = 0.f;
    #pragma unroll 4
    for (int j = 0; j < SS; j += 4) {
        a0 += prS[b * 64 + j]     * vbase[(size_t)j * DD];
        a1 += prS[b * 64 + j + 1] * vbase[(size_t)(j + 1) * DD];
        a2 += prS[b * 64 + j + 2] * vbase[(size_t)(j + 2) * DD];
        a3 += prS[b * 64 + j + 3] * vbase[(size_t)(j + 3) * DD];
    }
    attT[lane * 4 + b] = (a0 + a1) + (a2 + a3);
    __syncthreads();
    oproj_add(attT, Wco, h, aC, red);
}

// generic small-M GEMV kernel with fold inputs + extra residuals
template<int K, int NC>
__global__ __launch_bounds__(NTHR) void k_gemv(const float* __restrict__ A,
        const float* __restrict__ a1, const float* __restrict__ a2, const float* __restrict__ ln,
        const float* __restrict__ W, float* __restrict__ O, int ostr, int N,
        const float* __restrict__ res, const float* __restrict__ r1, const float* __restrict__ r2,
        int relu) {
    constexpr int C4N = NC / 4;
    constexpr int KSN = NTHR / C4N;
    constexpr int KC  = K / KSN;
    __shared__ float sm[K * 4 + 4096 + 4];
    float* hAT = sm;
    float* red = sm + K * 4;
    float* scl = sm + K * 4 + 4096;
    const int tid = threadIdx.x, lane = tid & 63, wv = tid >> 6;
    // pass 1: folded values
    for (int k = tid; k < K; k += NTHR) {
        float4 h;
        h.x = A[k]; h.y = A[K + k]; h.z = A[2 * K + k]; h.w = A[3 * K + k];
        if (a1) { h.x += a1[k]; h.y += a1[K + k]; h.z += a1[2 * K + k]; h.w += a1[3 * K + k]; }
        if (a2) { h.x += a2[k]; h.y += a2[K + k]; h.z += a2[2 * K + k]; h.w += a2[3 * K + k]; }
        *(float4*)(hAT + (size_t)k * 4) = h;
    }
    __syncthreads();
    if (ln) {
        float loc = 0.f;
        for (int k = lane; k < K; k += 64) { float x = hAT[k * 4 + wv]; loc += x * x; }
        for (int o = 32; o > 0; o >>= 1) loc += __shfl_xor(loc, o);
        if (lane == 0) scl[wv] = 1.0f / sqrtf(loc / K + EPSV);
        __syncthreads();
        float s0 = scl[0], s1 = scl[1], s2 = scl[2], s3 = scl[3];
        for (int k = tid; k < K; k += NTHR) {
            float lw = ln[k];
            float4 h = *(float4*)(hAT + (size_t)k * 4);
            h.x *= s0 * lw; h.y *= s1 * lw; h.z *= s2 * lw; h.w *= s3 * lw;
            *(float4*)(hAT + (size_t)k * 4) = h;
        }
    }
    __syncthreads();
    const int c4 = tid % C4N, ks = tid / C4N;
    const float4* W4 = (const float4*)W;
    const int col0 = blockIdx.x * NC;
    float acc[4][4] = {};
    const int kb = ks * KC;
    #pragma unroll 8
    for (int kk = 0; kk < KC; kk++) {
        int k = kb + kk;
        float4 w4 = W4[(size_t)k * (N >> 2) + (col0 >> 2) + c4];
        float4 h4 = *(float4*)(hAT + (size_t)k * 4);
        float hb[4] = {h4.x, h4.y, h4.z, h4.w};
        float wb[4] = {w4.x, w4.y, w4.z, w4.w};
        #pragma unroll
        for (int b = 0; b < 4; b++)
            #pragma unroll
            for (int ci = 0; ci < 4; ci++) acc[b][ci] += hb[b] * wb[ci];
    }
    {
        float* rp = red + (size_t)ks * (NC * 4) + c4 * 4;
        #pragma unroll
        for (int b = 0; b < 4; b++)
            #pragma unroll
            for (int ci = 0; ci < 4; ci++) rp[b * NC + ci] = acc[b][ci];
    }
    __syncthreads();
    for (int o = tid; o < 4 * NC; o += NTHR) {
        int b = o / NC, c = o % NC;
        float v = 0.f;
        #pragma unroll
        for (int k2 = 0; k2 < KSN; k2++) v += red[(size_t)k2 * (NC * 4) + o];
        size_t ix = (size_t)b * ostr + col0 + c;
        if (res) v += res[ix];
        if (r1)  v += r1[ix];
        if (r2)  v += r2[ix];
        if (relu) v = fmaxf(v, 0.f);
        O[ix] = v;
    }
}

// lm_head chunk (blocks 0..501) + stats; block 502 zeroes next-state + accs
__global__ __launch_bounds__(NTHR) void k_lmhead(const float* __restrict__ xc, float* __restrict__ xn,
        const float* __restrict__ lnf, const float* __restrict__ Wlm,
        float* __restrict__ lgb, float* __restrict__ stm, float* __restrict__ sts,
        int* __restrict__ stix, float* __restrict__ accb) {
    int blk = blockIdx.x, tid = threadIdx.x, lane = tid & 63, wave = tid >> 6;
    if (blk >= NCH) {
        for (int k = tid; k < BB * DD; k += NTHR) xn[k] = 0.f;
        for (int k = tid; k < 2 * LL * 2048; k += NTHR) accb[k] = 0.f;
        return;
    }
    __shared__ float hAT[2048];
    __shared__ float red[4096];
    __shared__ float msc[4];
    __shared__ float lgl[256];
    for (int k = tid; k < DD; k += NTHR) {
        float4 r;
        r.x = xc[k];          r.y = xc[DD + k];
        r.z = xc[2 * DD + k]; r.w = xc[3 * DD + k];
        *(float4*)(hAT + (size_t)k * 4) = r;
    }
    __syncthreads();
    {
        float loc = 0.f;
        for (int k = lane; k < DD; k += 64) { float x = hAT[k * 4 + wave]; loc += x * x; }
        for (int o = 32; o > 0; o >>= 1) loc += __shfl_xor(loc, o);
        if (lane == 0) msc[wave] = 1.0f / sqrtf(loc / DD + EPSV);
    }
    __syncthreads();
    float s0 = msc[0], s1 = msc[1], s2 = msc[2], s3 = msc[3];
    for (int k = tid; k < DD; k += NTHR) {
        float lw = lnf[k];
        float4 r = *(float4*)(hAT + (size_t)k * 4);
        r.x *= s0 * lw; r.y *= s1 * lw; r.z *= s2 * lw; r.w *= s3 * lw;
        *(float4*)(hAT + (size_t)k * 4) = r;
    }
    __syncthreads();
    {   // 64 cols, 16 c4-threads x 16 k-slices of 32
        int c4 = tid & 15, ks = tid >> 4;
        const float4* W4 = (const float4*)Wlm;
        float acc[4][4] = {};
        int kb = ks * 32;
        #pragma unroll
        for (int kk = 0; kk < 32; kk++) {
            int k = kb + kk;
            float4 w4 = W4[(size_t)k * (VV >> 2) + blk * 16 + c4];
            float4 h4 = *(float4*)(hAT + (size_t)k * 4);
            float hb[4] = {h4.x, h4.y, h4.z, h4.w};
            float wb[4] = {w4.x, w4.y, w4.z, w4.w};
            #pragma unroll
            for (int b = 0; b < 4; b++)
                #pragma unroll
                for (int ci = 0; ci < 4; ci++) acc[b][ci] += hb[b] * wb[ci];
        }
        float* rp = red + ks * 256 + c4 * 4;
        #pragma unroll
        for (int b = 0; b < 4; b++)
            #pragma unroll
            for (int ci = 0; ci < 4; ci++) rp[b * 64 + ci] = acc[b][ci];
    }
    __syncthreads();
    {
        float v = 0.f;
        #pragma unroll
        for (int k2 = 0; k2 < 16; k2++) v += red[k2 * 256 + tid];
        lgl[tid] = v;
        lgb[(size_t)(tid >> 6) * VV + blk * 64 + (tid & 63)] = v;
    }
    __syncthreads();
    {
        int b = wave;
        float v0 = lgl[b * 64 + lane];
        float mx = v0; int ix = lane;
        for (int o = 32; o > 0; o >>= 1) {
            float om = __shfl_xor(mx, o); int oi = __shfl_xor(ix, o);
            if (om > mx || (om == mx && oi < ix)) { mx = om; ix = oi; }
        }
        float s = expf(v0 - mx);
        for (int o = 32; o > 0; o >>= 1) s += __shfl_xor(s, o);
        if (lane == 0) {
            stm[b * STS + blk] = mx;
            sts[b * STS + blk] = s;
            stix[b * STS + blk] = blk * 64 + ix;
        }
    }
}

// merge stats + probs out + soft-emb partial -> xn; block 502 writes preds
__global__ __launch_bounds__(NTHR) void k_dmerge(const float* __restrict__ lgb,
        const float* __restrict__ stm, const float* __restrict__ sts, const int* __restrict__ stix,
        const float* __restrict__ emb, float* __restrict__ out, float* __restrict__ xn, int tt) {
    __shared__ float mM[8];
    __shared__ int jS[4];
    __shared__ float pT[256];
    __shared__ float red[4096];
    int blk = blockIdx.x, tid = threadIdx.x, lane = tid & 63, wave = tid >> 6;
    {   // merge per b (wave b)
        int b = wave;
        float M = -1e30f, S = 0.f; int jb = 0;
        for (int j = lane; j < NCH; j += 64) {
            float mj = stm[b * STS + j], sj = sts[b * STS + j];
            if (mj > M) { S = S * expf(M - mj) + sj; M = mj; jb = j; }
            else        { S += sj * expf(mj - M); }
        }
        for (int o = 32; o > 0; o >>= 1) {
            float Mo = __shfl_xor(M, o), So = __shfl_xor(S, o);
            int jo = __shfl_xor(jb, o);
            if (Mo > M || (Mo == M && jo < jb)) { S = S * expf(M - Mo) + So; M = Mo; jb = jo; }
            else { S += So * expf(Mo - M); }
        }
        if (lane == 0) { mM[b] = M; mM[4 + b] = S; jS[b] = jb; }
    }
    __syncthreads();
    if (blk < NCH) {
        {   // final probs for this chunk: write out + stash transposed
            int b = tid >> 6, c = tid & 63;
            float lg = lgb[(size_t)b * VV + blk * 64 + c];
            float p = expf(lg - mM[b]) / mM[4 + b];
            out[((size_t)b * TT + tt) * VV + blk * 64 + c] = p;
            pT[c * 4 + b] = p;
        }
        __syncthreads();
        {   // emb chunk (same 64 vocab rows as this block's logits)
            int c4 = tid & 127, rs = tid >> 7;
            const float4* E4 = (const float4*)emb;
            float4 a0 = {0,0,0,0}, a1 = a0, a2 = a0, a3 = a0;
            int rb = rs * 32;
            #pragma unroll 8
            for (int r = 0; r < 32; r++) {
                int row = rb + r;
                float4 e4 = E4[((size_t)(blk * 64 + row)) * 128 + c4];
                float4 p4 = *(float4*)(pT + row * 4);
                a0.x += p4.x * e4.x; a0.y += p4.x * e4.y; a0.z += p4.x * e4.z; a0.w += p4.x * e4.w;
                a1.x += p4.y * e4.x; a1.y += p4.y * e4.y; a1.z += p4.y * e4.z; a1.w += p4.y * e4.w;
                a2.x += p4.z * e4.x; a2.y += p4.z * e4.y; a2.z += p4.z * e4.z; a2.w += p4.z * e4.w;
                a3.x += p4.w * e4.x; a3.y += p4.w * e4.y; a3.z += p4.w * e4.z; a3.w += p4.w * e4.w;
            }
            float* rp = red + rs * 2048 + c4 * 4;
            rp[0]        = a0.x; rp[1]        = a0.y; rp[2]        = a0.z; rp[3]        = a0.w;
            rp[512 + 0]  = a1.x; rp[512 + 1]  = a1.y; rp[512 + 2]  = a1.z; rp[512 + 3]  = a1.w;
            rp[1024 + 0] = a2.x; rp[1024 + 1] = a2.y; rp[1024 + 2] = a2.z; rp[1024 + 3] = a2.w;
            rp[1536 + 0] = a3.x; rp[1536 + 1] = a3.y; rp[1536 + 2] = a3.z; rp[1536 + 3] = a3.w;
        }
        __syncthreads();
        #pragma unroll
        for (int i = 0; i < 8; i++) {
            int o = tid + i * 256;
            atomicAdd(xn + o, red[o] + red[2048 + o]);
        }
    } else {
        if (tid < 4) {   // pred flags
            int col = stix[tid * STS + jS[tid]];
            out[(size_t)BB * TT * VV + tid * TT + tt] = (col == 0) ? 1.0f : 0.0f;
        }
    }
}

// ===================== launch =============================================
extern "C" void kernel_launch(void* const* d_in, const int* in_sizes, int n_in,
                              void* d_out, int out_size, void* d_ws, size_t ws_size,
                              hipStream_t stream) {
    const int*   ids     = (const int*)  d_in[0];
    const float* mask    = (const float*)d_in[1];
    const float* emb     = (const float*)d_in[2];
    const float* enc_wq  = (const float*)d_in[3];
    const float* enc_wk  = (const float*)d_in[4];
    const float* enc_wv  = (const float*)d_in[5];
    const float* enc_wo  = (const float*)d_in[6];
    const float* enc_ln1 = (const float*)d_in[7];
    const float* enc_w1  = (const float*)d_in[8];
    const float* enc_w2  = (const float*)d_in[9];
    const float* enc_ln2 = (const float*)d_in[10];
    const float* enc_lnf = (const float*)d_in[11];
    const float* dec_sq  = (const float*)d_in[12];
    const float* dec_sk  = (const float*)d_in[13];
    const float* dec_sv  = (const float*)d_in[14];
    const float* dec_so  = (const float*)d_in[15];
    const float* dec_ln1 = (const float*)d_in[16];
    const float* dec_cq  = (const float*)d_in[17];
    const float* dec_ck  = (const float*)d_in[18];
    const float* dec_cv  = (const float*)d_in[19];
    const float* dec_co  = (const float*)d_in[20];
    const float* dec_ln2 = (const float*)d_in[21];
    const float* dec_w1  = (const float*)d_in[22];
    const float* dec_w2  = (const float*)d_in[23];
    const float* dec_ln3 = (const float*)d_in[24];
    const float* dec_lnf = (const float*)d_in[25];
    const float* lm_head = (const float*)d_in[26];
    float* out = (float*)d_out;

    // ---- workspace layout (floats) ----
    float* ws    = (float*)d_ws;
    float* xe    = ws;                                  // 131072
    float* qkv   = xe + BSDc;                           // 393216
    float* attb  = qkv + 3 * BSDc;                      // 131072
    float* ffbuf = attb + BSDc;                         // 524288
    float* cK    = ffbuf + (size_t)BB * SS * DFFF;      // 262144
    float* cV    = cK + LL * BSDc;                      // 262144
    float* sK    = cV + LL * BSDc;                      // 65536
    float* sV    = sK + (size_t)LL * BB * TT * DD;      // 65536
    float* xdA   = sV + (size_t)LL * BB * TT * DD;      // 2048
    float* xdB   = xdA + 2048;                          // 2048
    float* accb  = xdB + 2048;                          // 8192 (accS[2], accC[2])
    float* dff   = accb + 8192;                         // 8192
    float* stm   = dff + 8192;                          // 2048
    float* sts   = stm + 4 * STS;                       // 2048
    int*   stix  = (int*)(sts + 4 * STS);               // 2048
    float* lgb   = (float*)(stix) + 2048;               // 128512 (4*VV)

    // ---------- encoder (RMS folded into GEMMs) ----------
    k_embed<<<256, NTHR, 0, stream>>>(ids, emb, xe, xdA, accb);
    for (int l = 0; l < LL; l++) {
        k_qkv_f<<<96, NTHR, 0, stream>>>(xe, enc_ln1 + (size_t)l * DD,
                enc_wq + (size_t)l * DD2c, enc_wk + (size_t)l * DD2c, enc_wv + (size_t)l * DD2c, qkv);
        k_eattn<<<32, NTHR, 0, stream>>>(qkv, mask, attb);
        k_gemm<<<32, NTHR, 0, stream>>>(attb, enc_wo + (size_t)l * DD2c, xe, xe, 512, 512, 0);
        k_gemm_rms<<<128, NTHR, 0, stream>>>(xe, enc_ln2 + (size_t)l * DD,
                enc_w1 + (size_t)l * DD * DFFF, ffbuf, nullptr, 2048, 1);
        k_gemm<<<32, NTHR, 0, stream>>>(ffbuf, enc_w2 + (size_t)l * DFFF * DD, xe, xe, 2048, 512, 0);
    }
    k_ckcv_f<<<128, NTHR, 0, stream>>>(xe, enc_lnf, dec_ck, dec_cv, cK, cV);

    // ---------- decode ----------
    for (int tt = 0; tt < TT; tt++) {
        float* xc = (tt & 1) ? xdB : xdA;
        float* xn = (tt & 1) ? xdA : xdB;
        for (int l = 0; l < LL; l++) {
            float* aS = accb + (size_t)l * 2048;
            float* aC = accb + 4096 + (size_t)l * 2048;
            k_self<<<HH, NTHR, 0, stream>>>(xc, dec_ln1 + (size_t)l * DD,
                    dec_sq + (size_t)l * DD2c, dec_sk + (size_t)l * DD2c,
                    dec_sv + (size_t)l * DD2c, dec_so + (size_t)l * DD2c,
                    sK + (size_t)l * BB * TT * DD, sV + (size_t)l * BB * TT * DD, aS, tt);
            k_cross<<<HH, NTHR, 0, stream>>>(xc, aS, dec_ln2 + (size_t)l * DD,
                    dec_cq + (size_t)l * DD2c, dec_co + (size_t)l * DD2c,
                    cK + (size_t)l * BSDc, cV + (size_t)l * BSDc, mask, aC);
            k_gemv<512, 16><<<128, NTHR, 0, stream>>>(xc, aS, aC, dec_ln3 + (size_t)l * DD,
                    dec_w1 + (size_t)l * DD * DFFF, dff, DFFF, DFFF,
                    nullptr, nullptr, nullptr, 1);
            k_gemv<2048, 8><<<64, NTHR, 0, stream>>>(dff, nullptr, nullptr, nullptr,
                    dec_w2 + (size_t)l * DFFF * DD, xc, DD, 512,
                    xc, aS, aC, 0);
        }
        k_lmhead<<<NCH + 1, NTHR, 0, stream>>>(xc, xn, dec_lnf, lm_head, lgb, stm, sts, stix, accb);
        k_dmerge<<<NCH + 1, NTHR, 0, stream>>>(lgb, stm, sts, stix, emb, out, xn, tt);
    }
}

// Round 6
// 2532.548 us; speedup vs baseline: 2.2851x; 1.4905x over previous
//
#include <hip/hip_runtime.h>
#include <math.h>

#define BB   4
#define SS   64
#define DD   512
#define HH   8
#define DHH  64
#define DFFF 2048
#define LL   2
#define VV   32128
#define TT   16
#define EPSV 1e-6f
#define NEGB (-1e9f)
#define NTHR 256
#define NCH  502             // 502 * 64 = 32128 vocab columns
#define STS  512             // stride for per-chunk stat arrays

#define BSDc ((size_t)131072)    // B*S*D
#define DD2c ((size_t)262144)    // D*D

// ===================== encoder kernels ====================================

__global__ __launch_bounds__(NTHR) void k_embed(const int* __restrict__ ids,
        const float* __restrict__ emb, float* __restrict__ xe, float* __restrict__ xd,
        float* __restrict__ accb) {
    int blk = blockIdx.x, tid = threadIdx.x;
    int id = ids[blk];
    const float* src = emb + (size_t)id * DD;
    float* dst = xe + (size_t)blk * DD;
    for (int k = tid; k < DD; k += NTHR) dst[k] = src[k];
    if (blk < BB) {
        float* xdp = xd + (size_t)blk * DD;
        for (int k = tid; k < DD; k += NTHR) xdp[k] = emb[k];   // emb[PAD=0]
    }
    if (blk == 4) {
        for (int k = tid; k < 2 * LL * 2048; k += NTHR) accb[k] = 0.f;
    }
}

__global__ __launch_bounds__(NTHR) void k_rms(const float* __restrict__ x,
        const float* __restrict__ ln, float* __restrict__ h) {
    __shared__ float sm[NTHR];
    int row = blockIdx.x, tid = threadIdx.x;
    const float* xr = x + (size_t)row * DD;
    float local = 0.f;
    for (int k = tid; k < DD; k += NTHR) { float v = xr[k]; local += v * v; }
    sm[tid] = local; __syncthreads();
    for (int s = 128; s > 0; s >>= 1) { if (tid < s) sm[tid] += sm[tid + s]; __syncthreads(); }
    float scale = 1.0f / sqrtf(sm[0] / DD + EPSV);
    for (int k = tid; k < DD; k += NTHR) h[(size_t)row * DD + k] = xr[k] * scale * ln[k];
}

// -------- split-K partial GEMM: 64x64 tile over K-slice, double-buffered --
// A is [256 x K], W is [K x N]; writes 64x64 partial to P (4096 floats).
__device__ __forceinline__ void gemm_part(const float* __restrict__ A,
        const float* __restrict__ W, float* __restrict__ P,
        int K, int N, int tile, int ks, int kcnt, float* sm) {
    float* As0 = sm;                // [16][65]
    float* Ws0 = sm + 1040;        // [16][64]
    float* As1 = sm + 2064;
    float* Ws1 = sm + 3104;        // total 4128
    const int tid = threadIdx.x, tr = tid >> 4, tc = tid & 15;
    const int nb = N >> 6;
    const int row0 = (tile / nb) * 64, col0 = (tile % nb) * 64;
    const int arow = tid >> 4, acol = tid & 15;   // A: rows arow+j*16, k = acol
    const int wrow = tid >> 6, wcol = tid & 63;   // W: k rows wrow+j*4, col wcol
    const int kb = ks * kcnt * 16;
    float av[4], wv[4];
    {   // preload step 0
        int k0 = kb;
        #pragma unroll
        for (int j = 0; j < 4; j++) {
            av[j] = A[(size_t)(row0 + arow + j * 16) * K + k0 + acol];
            wv[j] = W[(size_t)(k0 + wrow + j * 4) * N + col0 + wcol];
        }
        #pragma unroll
        for (int j = 0; j < 4; j++) {
            As0[acol * 65 + arow + j * 16] = av[j];
            Ws0[(wrow + j * 4) * 64 + wcol] = wv[j];
        }
    }
    __syncthreads();
    float acc[4][4] = {};
    for (int s = 0; s < kcnt; s++) {
        float* Ac = (s & 1) ? As1 : As0;
        float* Wc = (s & 1) ? Ws1 : Ws0;
        if (s + 1 < kcnt) {   // prefetch next step into registers (overlaps compute)
            int k0 = kb + (s + 1) * 16;
            #pragma unroll
            for (int j = 0; j < 4; j++) {
                av[j] = A[(size_t)(row0 + arow + j * 16) * K + k0 + acol];
                wv[j] = W[(size_t)(k0 + wrow + j * 4) * N + col0 + wcol];
            }
        }
        #pragma unroll
        for (int kk = 0; kk < 16; kk++) {
            float a[4], b[4];
            #pragma unroll
            for (int j = 0; j < 4; j++) { a[j] = Ac[kk * 65 + tr * 4 + j]; b[j] = Wc[kk * 64 + tc * 4 + j]; }
            #pragma unroll
            for (int r = 0; r < 4; r++)
                #pragma unroll
                for (int c = 0; c < 4; c++) acc[r][c] += a[r] * b[c];
        }
        __syncthreads();
        if (s + 1 < kcnt) {
            float* An = (s & 1) ? As0 : As1;
            float* Wn = (s & 1) ? Ws0 : Ws1;
            #pragma unroll
            for (int j = 0; j < 4; j++) {
                An[acol * 65 + arow + j * 16] = av[j];
                Wn[(wrow + j * 4) * 64 + wcol] = wv[j];
            }
            __syncthreads();
        }
    }
    #pragma unroll
    for (int r = 0; r < 4; r++)
        #pragma unroll
        for (int c = 0; c < 4; c++)
            P[(tr * 4 + r) * 64 + tc * 4 + c] = acc[r][c];
}

// generic split-K partial kernel: grid = tiles*KS
template<int KS, int KCNT>
__global__ __launch_bounds__(NTHR) void k_sk(const float* __restrict__ A,
        const float* __restrict__ W, float* __restrict__ P, int K, int N) {
    __shared__ float sm[4128];
    int tile = blockIdx.x / KS, ks = blockIdx.x % KS;
    gemm_part(A, W, P + (size_t)blockIdx.x * 4096, K, N, tile, ks, KCNT, sm);
}

// qkv multiplexed: grid = 96*KS (m = tile-group/32)
template<int KS, int KCNT>
__global__ __launch_bounds__(NTHR) void k_qkvsk(const float* __restrict__ A,
        const float* __restrict__ wq, const float* __restrict__ wk, const float* __restrict__ wv,
        float* __restrict__ P) {
    __shared__ float sm[4128];
    int j = blockIdx.x / KS, ks = blockIdx.x % KS;
    int m = j >> 5, t2 = j & 31;
    const float* W = (m == 0) ? wq : (m == 1 ? wk : wv);
    gemm_part(A, W, P + (size_t)blockIdx.x * 4096, 512, 512, t2, ks, KCNT, sm);
}

// ckcv multiplexed: grid = 128*KS
template<int KS, int KCNT>
__global__ __launch_bounds__(NTHR) void k_ckcvsk(const float* __restrict__ A,
        const float* __restrict__ wck, const float* __restrict__ wcv, float* __restrict__ P) {
    __shared__ float sm[4128];
    int j = blockIdx.x / KS, ks = blockIdx.x % KS;
    int m = j >> 5, t2 = j & 31;
    const float* W = (m < 2) ? (wck + (size_t)m * DD2c) : (wcv + (size_t)(m - 2) * DD2c);
    gemm_part(A, W, P + (size_t)blockIdx.x * 4096, 512, 512, t2, ks, KCNT, sm);
}

// -------- split-K reductions ----------------------------------------------
__device__ __forceinline__ void red_part(const float* __restrict__ P, float* __restrict__ C,
        const float* __restrict__ res, int N, int relu, int tile, int sidx, int KS) {
    const int tid = threadIdx.x;
    const int nb = N >> 6;
    const int row0 = (tile / nb) * 64, col0 = (tile % nb) * 64;
    const float* Pb = P + (size_t)sidx * KS * 4096;
    for (int o = tid; o < 4096; o += NTHR) {
        float v = 0.f;
        for (int k = 0; k < KS; k++) v += Pb[(size_t)k * 4096 + o];
        int r = o >> 6, c = o & 63;
        size_t ix = (size_t)(row0 + r) * N + col0 + c;
        if (res) v += res[ix];
        if (relu) v = fmaxf(v, 0.f);
        C[ix] = v;
    }
}

template<int KS>
__global__ __launch_bounds__(NTHR) void k_red(const float* __restrict__ P, float* __restrict__ C,
        const float* __restrict__ res, int N, int relu) {
    red_part(P, C, res, N, relu, blockIdx.x, blockIdx.x, KS);
}

template<int KS>
__global__ __launch_bounds__(NTHR) void k_qkvred(const float* __restrict__ P, float* __restrict__ qkv) {
    int j = blockIdx.x, m = j >> 5, t2 = j & 31;
    red_part(P, qkv + (size_t)m * BSDc, nullptr, 512, 0, t2, j, KS);
}

template<int KS>
__global__ __launch_bounds__(NTHR) void k_ckcvred(const float* __restrict__ P,
        float* __restrict__ cK, float* __restrict__ cV) {
    int j = blockIdx.x, m = j >> 5, t2 = j & 31;
    float* C = (m < 2) ? (cK + (size_t)m * BSDc) : (cV + (size_t)(m - 2) * BSDc);
    red_part(P, C, nullptr, 512, 0, t2, j, KS);
}

__global__ __launch_bounds__(NTHR) void k_eattn(const float* __restrict__ qkv,
        const float* __restrict__ mask, float* __restrict__ o) {
    __shared__ float sm[3 * 64 * 65];
    int job = blockIdx.x;
    int b = job / HH, h = job % HH;
    int tid = threadIdx.x;
    int lane = tid & 63, wave = tid >> 6;
    float* qq = sm;
    float* kk = sm + 64 * 65;
    float* vv = sm + 2 * 64 * 65;
    for (int i = tid; i < SS * DHH; i += NTHR) {
        int s = i >> 6, d = i & 63;
        size_t src = (size_t)(b * SS + s) * DD + h * DHH + d;
        qq[s * 65 + d] = qkv[src];
        kk[s * 65 + d] = qkv[BSDc + src];
        vv[s * 65 + d] = qkv[2 * BSDc + src];
    }
    __syncthreads();
    float bias = (1.0f - mask[b * SS + lane]) * NEGB;
    for (int r = 0; r < 16; r++) {
        int s = wave * 16 + r;
        float sc = 0.f;
        for (int i = 0; i < DHH; i++) sc += qq[s * 65 + i] * kk[lane * 65 + i];
        sc = sc * 0.125f + bias;
        float m = sc;
        for (int o2 = 32; o2 > 0; o2 >>= 1) m = fmaxf(m, __shfl_xor(m, o2));
        float e = expf(sc - m);
        float sum = e;
        for (int o2 = 32; o2 > 0; o2 >>= 1) sum += __shfl_xor(sum, o2);
        float p = e / sum;
        float acc = 0.f;
        for (int t2 = 0; t2 < SS; t2++) acc += __shfl(p, t2) * vv[t2 * 65 + lane];
        o[(size_t)(b * SS + s) * DD + h * DHH + lane] = acc;
    }
}

// ===================== decode building blocks (unchanged, round-5) ========

__device__ __forceinline__ void build_hAT(const float* __restrict__ A, const float* __restrict__ a1,
        const float* __restrict__ a2, const float* __restrict__ ln, float* hAT, float* scl) {
    const int tid = threadIdx.x, lane = tid & 63, wv = tid >> 6;
    for (int k = tid; k < DD; k += NTHR) {
        float4 h;
        h.x = A[k]; h.y = A[DD + k]; h.z = A[2 * DD + k]; h.w = A[3 * DD + k];
        if (a1) { h.x += a1[k]; h.y += a1[DD + k]; h.z += a1[2 * DD + k]; h.w += a1[3 * DD + k]; }
        if (a2) { h.x += a2[k]; h.y += a2[DD + k]; h.z += a2[2 * DD + k]; h.w += a2[3 * DD + k]; }
        *(float4*)(hAT + (size_t)k * 4) = h;
    }
    __syncthreads();
    float loc = 0.f;
    for (int k = lane; k < DD; k += 64) { float x = hAT[k * 4 + wv]; loc += x * x; }
    for (int o = 32; o > 0; o >>= 1) loc += __shfl_xor(loc, o);
    if (lane == 0) scl[wv] = 1.0f / sqrtf(loc / DD + EPSV);
    __syncthreads();
    float s0 = scl[0], s1 = scl[1], s2 = scl[2], s3 = scl[3];
    for (int k = tid; k < DD; k += NTHR) {
        float lw = ln[k];
        float4 h = *(float4*)(hAT + (size_t)k * 4);
        h.x *= s0 * lw; h.y *= s1 * lw; h.z *= s2 * lw; h.w *= s3 * lw;
        *(float4*)(hAT + (size_t)k * 4) = h;
    }
    __syncthreads();
}

template<int K, int NC>
__device__ __forceinline__ void gemv_core(const float* hAT, const float* __restrict__ W,
        int N, int col0, float* red, float* outL) {
    constexpr int C4N = NC / 4;
    constexpr int KSN = NTHR / C4N;
    constexpr int KC  = K / KSN;
    const int tid = threadIdx.x;
    const int c4 = tid % C4N, ks = tid / C4N;
    const float4* W4 = (const float4*)W;
    float acc[4][4] = {};
    const int kb = ks * KC;
    #pragma unroll 8
    for (int kk = 0; kk < KC; kk++) {
        int k = kb + kk;
        float4 w4 = W4[(size_t)k * (N >> 2) + (col0 >> 2) + c4];
        float4 h4 = *(const float4*)(hAT + (size_t)k * 4);
        float hb[4] = {h4.x, h4.y, h4.z, h4.w};
        float wb[4] = {w4.x, w4.y, w4.z, w4.w};
        #pragma unroll
        for (int b = 0; b < 4; b++)
            #pragma unroll
            for (int ci = 0; ci < 4; ci++) acc[b][ci] += hb[b] * wb[ci];
    }
    {
        float* rp = red + (size_t)ks * (NC * 4) + c4 * 4;
        #pragma unroll
        for (int b = 0; b < 4; b++)
            #pragma unroll
            for (int ci = 0; ci < 4; ci++) rp[b * NC + ci] = acc[b][ci];
    }
    __syncthreads();
    for (int o = tid; o < 4 * NC; o += NTHR) {
        float v = 0.f;
        #pragma unroll
        for (int k2 = 0; k2 < KSN; k2++) v += red[(size_t)k2 * (NC * 4) + o];
        outL[o] = v;
    }
    __syncthreads();
}

__device__ __forceinline__ void oproj_add(const float* attT, const float* __restrict__ Wo,
        int h, float* accD, float* red) {
    const int tid = threadIdx.x;
    const int c4 = tid & 127, ks = tid >> 7;
    const float4* W4 = (const float4*)Wo;
    float ac[4][4] = {};
    const int db = ks * 32;
    #pragma unroll 8
    for (int dd = 0; dd < 32; dd++) {
        int d = db + dd;
        float4 w4 = W4[(size_t)(h * DHH + d) * 128 + c4];
        float wb[4] = {w4.x, w4.y, w4.z, w4.w};
        #pragma unroll
        for (int bb = 0; bb < 4; bb++) {
            float av = attT[d * 4 + bb];
            #pragma unroll
            for (int ci = 0; ci < 4; ci++) ac[bb][ci] += av * wb[ci];
        }
    }
    {
        float* rp = red + ks * 2048 + c4 * 4;
        #pragma unroll
        for (int bb = 0; bb < 4; bb++)
            #pragma unroll
            for (int ci = 0; ci < 4; ci++) rp[bb * 512 + ci] = ac[bb][ci];
    }
    __syncthreads();
    for (int o = tid; o < 2048; o += NTHR) {
        atomicAdd(accD + o, red[o] + red[2048 + o]);
    }
}

__global__ __launch_bounds__(NTHR) void k_self(const float* __restrict__ xc,
        const float* __restrict__ ln1, const float* __restrict__ Wq,
        const float* __restrict__ Wk, const float* __restrict__ Wv,
        const float* __restrict__ Wso, float* __restrict__ sKl, float* __restrict__ sVl,
        float* __restrict__ aS, int tt) {
    __shared__ float hAT[2048];
    __shared__ float red[4096];
    __shared__ float scl[4];
    __shared__ float qh[256];
    __shared__ float kh[256];
    __shared__ float vh[256];
    __shared__ float attT[256];
    const int h = blockIdx.x;
    const int tid = threadIdx.x, lane = tid & 63, b = tid >> 6;

    build_hAT(xc, nullptr, nullptr, ln1, hAT, scl);
    gemv_core<512, 64>(hAT, Wq, 512, h * 64, red, qh);
    gemv_core<512, 64>(hAT, Wk, 512, h * 64, red, kh);
    gemv_core<512, 64>(hAT, Wv, 512, h * 64, red, vh);
    {
        int c = tid & 63;
        size_t dst = ((size_t)b * TT + tt) * DD + h * DHH + c;
        sKl[dst] = kh[tid];
        sVl[dst] = vh[tid];
    }
    float sc = -1e30f;
    if (lane <= tt) {
        float s2 = 0.f;
        if (lane == tt) {
            #pragma unroll 16
            for (int i = 0; i < DHH; i++) s2 += qh[b * 64 + i] * kh[b * 64 + i];
        } else {
            const float* kr = sKl + ((size_t)b * TT + lane) * DD + h * DHH;
            #pragma unroll 16
            for (int i = 0; i < DHH; i++) s2 += qh[b * 64 + i] * kr[i];
        }
        sc = s2 * 0.125f;
    }
    float m = sc;
    for (int o2 = 32; o2 > 0; o2 >>= 1) m = fmaxf(m, __shfl_xor(m, o2));
    float e = (lane <= tt) ? expf(sc - m) : 0.f;
    float sum = e;
    for (int o2 = 32; o2 > 0; o2 >>= 1) sum += __shfl_xor(sum, o2);
    float pr = e / sum;
    float acc = 0.f;
    for (int j = 0; j < tt; j++) {
        float pj = __shfl(pr, j);
        acc += pj * sVl[((size_t)b * TT + j) * DD + h * DHH + lane];
    }
    acc += __shfl(pr, tt) * vh[b * 64 + lane];
    attT[lane * 4 + b] = acc;
    __syncthreads();
    oproj_add(attT, Wso, h, aS, red);
}

__global__ __launch_bounds__(NTHR) void k_cross(const float* __restrict__ xc,
        const float* __restrict__ aS, const float* __restrict__ ln2,
        const float* __restrict__ Wcq, const float* __restrict__ Wco,
        const float* __restrict__ cKl, const float* __restrict__ cVl,
        const float* __restrict__ mask, float* __restrict__ aC) {
    __shared__ float hAT[2048];
    __shared__ float red[4096];
    __shared__ float scl[4];
    __shared__ float qh[256];
    __shared__ float prS[256];
    __shared__ float attT[256];
    const int h = blockIdx.x;
    const int tid = threadIdx.x, lane = tid & 63, b = tid >> 6;

    build_hAT(xc, aS, nullptr, ln2, hAT, scl);
    gemv_core<512, 64>(hAT, Wcq, 512, h * 64, red, qh);
    const float* kr = cKl + ((size_t)b * SS + lane) * DD + h * DHH;
    float s2 = 0.f;
    #pragma unroll 16
    for (int i = 0; i < DHH; i++) s2 += qh[b * 64 + i] * kr[i];
    float sc = s2 * 0.125f + (1.0f - mask[b * SS + lane]) * NEGB;
    float m = sc;
    for (int o2 = 32; o2 > 0; o2 >>= 1) m = fmaxf(m, __shfl_xor(m, o2));
    float e = expf(sc - m);
    float sum = e;
    for (int o2 = 32; o2 > 0; o2 >>= 1) sum += __shfl_xor(sum, o2);
    prS[b * 64 + lane] = e / sum;
    const float* vbase = cVl + (size_t)b * SS * DD + h * DHH + lane;
    float a0 = 0.f, a1 = 0.f, a2 = 0.f, a3 = 0.f;
    #pragma unroll 4
    for (int j = 0; j < SS; j += 4) {
        a0 += prS[b * 64 + j]     * vbase[(size_t)j * DD];
        a1 += prS[b * 64 + j + 1] * vbase[(size_t)(j + 1) * DD];
        a2 += prS[b * 64 + j + 2] * vbase[(size_t)(j + 2) * DD];
        a3 += prS[b * 64 + j + 3] * vbase[(size_t)(j + 3) * DD];
    }
    attT[lane * 4 + b] = (a0 + a1) + (a2 + a3);
    __syncthreads();
    oproj_add(attT, Wco, h, aC, red);
}

template<int K, int NC>
__global__ __launch_bounds__(NTHR) void k_gemv(const float* __restrict__ A,
        const float* __restrict__ a1, const float* __restrict__ a2, const float* __restrict__ ln,
        const float* __restrict__ W, float* __restrict__ O, int ostr, int N,
        const float* __restrict__ res, const float* __restrict__ r1, const float* __restrict__ r2,
        int relu) {
    constexpr int C4N = NC / 4;
    constexpr int KSN = NTHR / C4N;
    constexpr int KC  = K / KSN;
    __shared__ float sm[K * 4 + 4096 + 4];
    float* hAT = sm;
    float* red = sm + K * 4;
    float* scl = sm + K * 4 + 4096;
    const int tid = threadIdx.x, lane = tid & 63, wv = tid >> 6;
    for (int k = tid; k < K; k += NTHR) {
        float4 h;
        h.x = A[k]; h.y = A[K + k]; h.z = A[2 * K + k]; h.w = A[3 * K + k];
        if (a1) { h.x += a1[k]; h.y += a1[K + k]; h.z += a1[2 * K + k]; h.w += a1[3 * K + k]; }
        if (a2) { h.x += a2[k]; h.y += a2[K + k]; h.z += a2[2 * K + k]; h.w += a2[3 * K + k]; }
        *(float4*)(hAT + (size_t)k * 4) = h;
    }
    __syncthreads();
    if (ln) {
        float loc = 0.f;
        for (int k = lane; k < K; k += 64) { float x = hAT[k * 4 + wv]; loc += x * x; }
        for (int o = 32; o > 0; o >>= 1) loc += __shfl_xor(loc, o);
        if (lane == 0) scl[wv] = 1.0f / sqrtf(loc / K + EPSV);
        __syncthreads();
        float s0 = scl[0], s1 = scl[1], s2 = scl[2], s3 = scl[3];
        for (int k = tid; k < K; k += NTHR) {
            float lw = ln[k];
            float4 h = *(float4*)(hAT + (size_t)k * 4);
            h.x *= s0 * lw; h.y *= s1 * lw; h.z *= s2 * lw; h.w *= s3 * lw;
            *(float4*)(hAT + (size_t)k * 4) = h;
        }
    }
    __syncthreads();
    const int c4 = tid % C4N, ks = tid / C4N;
    const float4* W4 = (const float4*)W;
    const int col0 = blockIdx.x * NC;
    float acc[4][4] = {};
    const int kb = ks * KC;
    #pragma unroll 8
    for (int kk = 0; kk < KC; kk++) {
        int k = kb + kk;
        float4 w4 = W4[(size_t)k * (N >> 2) + (col0 >> 2) + c4];
        float4 h4 = *(float4*)(hAT + (size_t)k * 4);
        float hb[4] = {h4.x, h4.y, h4.z, h4.w};
        float wb[4] = {w4.x, w4.y, w4.z, w4.w};
        #pragma unroll
        for (int b = 0; b < 4; b++)
            #pragma unroll
            for (int ci = 0; ci < 4; ci++) acc[b][ci] += hb[b] * wb[ci];
    }
    {
        float* rp = red + (size_t)ks * (NC * 4) + c4 * 4;
        #pragma unroll
        for (int b = 0; b < 4; b++)
            #pragma unroll
            for (int ci = 0; ci < 4; ci++) rp[b * NC + ci] = acc[b][ci];
    }
    __syncthreads();
    for (int o = tid; o < 4 * NC; o += NTHR) {
        int b = o / NC, c = o % NC;
        float v = 0.f;
        #pragma unroll
        for (int k2 = 0; k2 < KSN; k2++) v += red[(size_t)k2 * (NC * 4) + o];
        size_t ix = (size_t)b * ostr + col0 + c;
        if (res) v += res[ix];
        if (r1)  v += r1[ix];
        if (r2)  v += r2[ix];
        if (relu) v = fmaxf(v, 0.f);
        O[ix] = v;
    }
}

__global__ __launch_bounds__(NTHR) void k_lmhead(const float* __restrict__ xc, float* __restrict__ xn,
        const float* __restrict__ lnf, const float* __restrict__ Wlm,
        float* __restrict__ lgb, float* __restrict__ stm, float* __restrict__ sts,
        int* __restrict__ stix, float* __restrict__ accb) {
    int blk = blockIdx.x, tid = threadIdx.x, lane = tid & 63, wave = tid >> 6;
    if (blk >= NCH) {
        for (int k = tid; k < BB * DD; k += NTHR) xn[k] = 0.f;
        for (int k = tid; k < 2 * LL * 2048; k += NTHR) accb[k] = 0.f;
        return;
    }
    __shared__ float hAT[2048];
    __shared__ float red[4096];
    __shared__ float msc[4];
    __shared__ float lgl[256];
    for (int k = tid; k < DD; k += NTHR) {
        float4 r;
        r.x = xc[k];          r.y = xc[DD + k];
        r.z = xc[2 * DD + k]; r.w = xc[3 * DD + k];
        *(float4*)(hAT + (size_t)k * 4) = r;
    }
    __syncthreads();
    {
        float loc = 0.f;
        for (int k = lane; k < DD; k += 64) { float x = hAT[k * 4 + wave]; loc += x * x; }
        for (int o = 32; o > 0; o >>= 1) loc += __shfl_xor(loc, o);
        if (lane == 0) msc[wave] = 1.0f / sqrtf(loc / DD + EPSV);
    }
    __syncthreads();
    float s0 = msc[0], s1 = msc[1], s2 = msc[2], s3 = msc[3];
    for (int k = tid; k < DD; k += NTHR) {
        float lw = lnf[k];
        float4 r = *(float4*)(hAT + (size_t)k * 4);
        r.x *= s0 * lw; r.y *= s1 * lw; r.z *= s2 * lw; r.w *= s3 * lw;
        *(float4*)(hAT + (size_t)k * 4) = r;
    }
    __syncthreads();
    {
        int c4 = tid & 15, ks = tid >> 4;
        const float4* W4 = (const float4*)Wlm;
        float acc[4][4] = {};
        int kb = ks * 32;
        #pragma unroll
        for (int kk = 0; kk < 32; kk++) {
            int k = kb + kk;
            float4 w4 = W4[(size_t)k * (VV >> 2) + blk * 16 + c4];
            float4 h4 = *(float4*)(hAT + (size_t)k * 4);
            float hb[4] = {h4.x, h4.y, h4.z, h4.w};
            float wb[4] = {w4.x, w4.y, w4.z, w4.w};
            #pragma unroll
            for (int b = 0; b < 4; b++)
                #pragma unroll
                for (int ci = 0; ci < 4; ci++) acc[b][ci] += hb[b] * wb[ci];
        }
        float* rp = red + ks * 256 + c4 * 4;
        #pragma unroll
        for (int b = 0; b < 4; b++)
            #pragma unroll
            for (int ci = 0; ci < 4; ci++) rp[b * 64 + ci] = acc[b][ci];
    }
    __syncthreads();
    {
        float v = 0.f;
        #pragma unroll
        for (int k2 = 0; k2 < 16; k2++) v += red[k2 * 256 + tid];
        lgl[tid] = v;
        lgb[(size_t)(tid >> 6) * VV + blk * 64 + (tid & 63)] = v;
    }
    __syncthreads();
    {
        int b = wave;
        float v0 = lgl[b * 64 + lane];
        float mx = v0; int ix = lane;
        for (int o = 32; o > 0; o >>= 1) {
            float om = __shfl_xor(mx, o); int oi = __shfl_xor(ix, o);
            if (om > mx || (om == mx && oi < ix)) { mx = om; ix = oi; }
        }
        float s = expf(v0 - mx);
        for (int o = 32; o > 0; o >>= 1) s += __shfl_xor(s, o);
        if (lane == 0) {
            stm[b * STS + blk] = mx;
            sts[b * STS + blk] = s;
            stix[b * STS + blk] = blk * 64 + ix;
        }
    }
}

__global__ __launch_bounds__(NTHR) void k_dmerge(const float* __restrict__ lgb,
        const float* __restrict__ stm, const float* __restrict__ sts, const int* __restrict__ stix,
        const float* __restrict__ emb, float* __restrict__ out, float* __restrict__ xn, int tt) {
    __shared__ float mM[8];
    __shared__ int jS[4];
    __shared__ float pT[256];
    __shared__ float red[4096];
    int blk = blockIdx.x, tid = threadIdx.x, lane = tid & 63, wave = tid >> 6;
    {
        int b = wave;
        float M = -1e30f, S = 0.f; int jb = 0;
        for (int j = lane; j < NCH; j += 64) {
            float mj = stm[b * STS + j], sj = sts[b * STS + j];
            if (mj > M) { S = S * expf(M - mj) + sj; M = mj; jb = j; }
            else        { S += sj * expf(mj - M); }
        }
        for (int o = 32; o > 0; o >>= 1) {
            float Mo = __shfl_xor(M, o), So = __shfl_xor(S, o);
            int jo = __shfl_xor(jb, o);
            if (Mo > M || (Mo == M && jo < jb)) { S = S * expf(M - Mo) + So; M = Mo; jb = jo; }
            else { S += So * expf(Mo - M); }
        }
        if (lane == 0) { mM[b] = M; mM[4 + b] = S; jS[b] = jb; }
    }
    __syncthreads();
    if (blk < NCH) {
        {
            int b = tid >> 6, c = tid & 63;
            float lg = lgb[(size_t)b * VV + blk * 64 + c];
            float p = expf(lg - mM[b]) / mM[4 + b];
            out[((size_t)b * TT + tt) * VV + blk * 64 + c] = p;
            pT[c * 4 + b] = p;
        }
        __syncthreads();
        {
            int c4 = tid & 127, rs = tid >> 7;
            const float4* E4 = (const float4*)emb;
            float4 a0 = {0,0,0,0}, a1 = a0, a2 = a0, a3 = a0;
            int rb = rs * 32;
            #pragma unroll 8
            for (int r = 0; r < 32; r++) {
                int row = rb + r;
                float4 e4 = E4[((size_t)(blk * 64 + row)) * 128 + c4];
                float4 p4 = *(float4*)(pT + row * 4);
                a0.x += p4.x * e4.x; a0.y += p4.x * e4.y; a0.z += p4.x * e4.z; a0.w += p4.x * e4.w;
                a1.x += p4.y * e4.x; a1.y += p4.y * e4.y; a1.z += p4.y * e4.z; a1.w += p4.y * e4.w;
                a2.x += p4.z * e4.x; a2.y += p4.z * e4.y; a2.z += p4.z * e4.z; a2.w += p4.z * e4.w;
                a3.x += p4.w * e4.x; a3.y += p4.w * e4.y; a3.z += p4.w * e4.z; a3.w += p4.w * e4.w;
            }
            float* rp = red + rs * 2048 + c4 * 4;
            rp[0]        = a0.x; rp[1]        = a0.y; rp[2]        = a0.z; rp[3]        = a0.w;
            rp[512 + 0]  = a1.x; rp[512 + 1]  = a1.y; rp[512 + 2]  = a1.z; rp[512 + 3]  = a1.w;
            rp[1024 + 0] = a2.x; rp[1024 + 1] = a2.y; rp[1024 + 2] = a2.z; rp[1024 + 3] = a2.w;
            rp[1536 + 0] = a3.x; rp[1536 + 1] = a3.y; rp[1536 + 2] = a3.z; rp[1536 + 3] = a3.w;
        }
        __syncthreads();
        #pragma unroll
        for (int i = 0; i < 8; i++) {
            int o = tid + i * 256;
            atomicAdd(xn + o, red[o] + red[2048 + o]);
        }
    } else {
        if (tid < 4) {
            int col = stix[tid * STS + jS[tid]];
            out[(size_t)BB * TT * VV + tid * TT + tt] = (col == 0) ? 1.0f : 0.0f;
        }
    }
}

// ===================== launch =============================================
extern "C" void kernel_launch(void* const* d_in, const int* in_sizes, int n_in,
                              void* d_out, int out_size, void* d_ws, size_t ws_size,
                              hipStream_t stream) {
    const int*   ids     = (const int*)  d_in[0];
    const float* mask    = (const float*)d_in[1];
    const float* emb     = (const float*)d_in[2];
    const float* enc_wq  = (const float*)d_in[3];
    const float* enc_wk  = (const float*)d_in[4];
    const float* enc_wv  = (const float*)d_in[5];
    const float* enc_wo  = (const float*)d_in[6];
    const float* enc_ln1 = (const float*)d_in[7];
    const float* enc_w1  = (const float*)d_in[8];
    const float* enc_w2  = (const float*)d_in[9];
    const float* enc_ln2 = (const float*)d_in[10];
    const float* enc_lnf = (const float*)d_in[11];
    const float* dec_sq  = (const float*)d_in[12];
    const float* dec_sk  = (const float*)d_in[13];
    const float* dec_sv  = (const float*)d_in[14];
    const float* dec_so  = (const float*)d_in[15];
    const float* dec_ln1 = (const float*)d_in[16];
    const float* dec_cq  = (const float*)d_in[17];
    const float* dec_ck  = (const float*)d_in[18];
    const float* dec_cv  = (const float*)d_in[19];
    const float* dec_co  = (const float*)d_in[20];
    const float* dec_ln2 = (const float*)d_in[21];
    const float* dec_w1  = (const float*)d_in[22];
    const float* dec_w2  = (const float*)d_in[23];
    const float* dec_ln3 = (const float*)d_in[24];
    const float* dec_lnf = (const float*)d_in[25];
    const float* lm_head = (const float*)d_in[26];
    float* out = (float*)d_out;

    // ---- workspace layout (floats) ----
    float* ws    = (float*)d_ws;
    float* xe    = ws;                                  // 131072
    float* qkv   = xe + BSDc;                           // 393216
    float* hbuf  = qkv + 3 * BSDc;                      // 131072
    float* attb  = hbuf + BSDc;                         // 131072
    float* ffbuf = attb + BSDc;                         // 524288
    float* cK    = ffbuf + (size_t)BB * SS * DFFF;      // 262144
    float* cV    = cK + LL * BSDc;                      // 262144
    float* sK    = cV + LL * BSDc;                      // 65536
    float* sV    = sK + (size_t)LL * BB * TT * DD;      // 65536
    float* xdA   = sV + (size_t)LL * BB * TT * DD;      // 2048
    float* xdB   = xdA + 2048;                          // 2048
    float* accb  = xdB + 2048;                          // 8192
    float* dff   = accb + 8192;                         // 8192
    float* stm   = dff + 8192;                          // 2048
    float* sts   = stm + 4 * STS;                       // 2048
    int*   stix  = (int*)(sts + 4 * STS);               // 2048
    float* lgb   = (float*)(stix) + 2048;               // 128512 (4*VV)
    float* skb   = lgb + 4 * VV;                        // 2097152 split-K scratch

    // ---------- encoder (split-K + double-buffered GEMMs) ----------
    k_embed<<<256, NTHR, 0, stream>>>(ids, emb, xe, xdA, accb);
    for (int l = 0; l < LL; l++) {
        k_rms<<<256, NTHR, 0, stream>>>(xe, enc_ln1 + (size_t)l * DD, hbuf);
        k_qkvsk<4, 8><<<384, NTHR, 0, stream>>>(hbuf, enc_wq + (size_t)l * DD2c,
                enc_wk + (size_t)l * DD2c, enc_wv + (size_t)l * DD2c, skb);
        k_qkvred<4><<<96, NTHR, 0, stream>>>(skb, qkv);
        k_eattn<<<32, NTHR, 0, stream>>>(qkv, mask, attb);
        k_sk<8, 4><<<256, NTHR, 0, stream>>>(attb, enc_wo + (size_t)l * DD2c, skb, 512, 512);
        k_red<8><<<32, NTHR, 0, stream>>>(skb, xe, xe, 512, 0);
        k_rms<<<256, NTHR, 0, stream>>>(xe, enc_ln2 + (size_t)l * DD, hbuf);
        k_sk<4, 8><<<512, NTHR, 0, stream>>>(hbuf, enc_w1 + (size_t)l * DD * DFFF, skb, 512, 2048);
        k_red<4><<<128, NTHR, 0, stream>>>(skb, ffbuf, nullptr, 2048, 1);
        k_sk<16, 8><<<512, NTHR, 0, stream>>>(ffbuf, enc_w2 + (size_t)l * DFFF * DD, skb, 2048, 512);
        k_red<16><<<32, NTHR, 0, stream>>>(skb, xe, xe, 512, 0);
    }
    k_rms<<<256, NTHR, 0, stream>>>(xe, enc_lnf, hbuf);
    k_ckcvsk<4, 8><<<512, NTHR, 0, stream>>>(hbuf, dec_ck, dec_cv, skb);
    k_ckcvred<4><<<128, NTHR, 0, stream>>>(skb, cK, cV);

    // ---------- decode (unchanged round-5 structure) ----------
    for (int tt = 0; tt < TT; tt++) {
        float* xc = (tt & 1) ? xdB : xdA;
        float* xn = (tt & 1) ? xdA : xdB;
        for (int l = 0; l < LL; l++) {
            float* aS = accb + (size_t)l * 2048;
            float* aC = accb + 4096 + (size_t)l * 2048;
            k_self<<<HH, NTHR, 0, stream>>>(xc, dec_ln1 + (size_t)l * DD,
                    dec_sq + (size_t)l * DD2c, dec_sk + (size_t)l * DD2c,
                    dec_sv + (size_t)l * DD2c, dec_so + (size_t)l * DD2c,
                    sK + (size_t)l * BB * TT * DD, sV + (size_t)l * BB * TT * DD, aS, tt);
            k_cross<<<HH, NTHR, 0, stream>>>(xc, aS, dec_ln2 + (size_t)l * DD,
                    dec_cq + (size_t)l * DD2c, dec_co + (size_t)l * DD2c,
                    cK + (size_t)l * BSDc, cV + (size_t)l * BSDc, mask, aC);
            k_gemv<512, 16><<<128, NTHR, 0, stream>>>(xc, aS, aC, dec_ln3 + (size_t)l * DD,
                    dec_w1 + (size_t)l * DD * DFFF, dff, DFFF, DFFF,
                    nullptr, nullptr, nullptr, 1);
            k_gemv<2048, 8><<<64, NTHR, 0, stream>>>(dff, nullptr, nullptr, nullptr,
                    dec_w2 + (size_t)l * DFFF * DD, xc, DD, 512,
                    xc, aS, aC, 0);
        }
        k_lmhead<<<NCH + 1, NTHR, 0, stream>>>(xc, xn, dec_lnf, lm_head, lgb, stm, sts, stix, accb);
        k_dmerge<<<NCH + 1, NTHR, 0, stream>>>(lgb, stm, sts, stix, emb, out, xn, tt);
    }
}

// Round 7
// 2366.622 us; speedup vs baseline: 2.4453x; 1.0701x over previous
//
#include <hip/hip_runtime.h>
#include <math.h>

#define BB   4
#define SS   64
#define DD   512
#define HH   8
#define DHH  64
#define DFFF 2048
#define LL   2
#define VV   32128
#define TT   16
#define EPSV 1e-6f
#define NEGB (-1e9f)
#define NTHR 256
#define NCH  502             // 502 * 64 = 32128 vocab columns
#define STS  512             // stride for per-chunk stat arrays
#define NACCT (3 * LL)       // accumulator slots: [aS0,aC0,aF0,aS1,aC1,aF1]

#define BSDc ((size_t)131072)    // B*S*D
#define DD2c ((size_t)262144)    // D*D

// ===================== encoder kernels ====================================

__global__ __launch_bounds__(NTHR) void k_embed(const int* __restrict__ ids,
        const float* __restrict__ emb, float* __restrict__ xe, float* __restrict__ xd,
        float* __restrict__ accb) {
    int blk = blockIdx.x, tid = threadIdx.x;
    int id = ids[blk];
    const float* src = emb + (size_t)id * DD;
    float* dst = xe + (size_t)blk * DD;
    for (int k = tid; k < DD; k += NTHR) dst[k] = src[k];
    if (blk < BB) {
        float* xdp = xd + (size_t)blk * DD;
        for (int k = tid; k < DD; k += NTHR) xdp[k] = emb[k];   // emb[PAD=0]
    }
    if (blk == 4) {
        for (int k = tid; k < NACCT * 2048; k += NTHR) accb[k] = 0.f;
    }
}

__global__ __launch_bounds__(NTHR) void k_rms(const float* __restrict__ x,
        const float* __restrict__ ln, float* __restrict__ h) {
    __shared__ float sm[NTHR];
    int row = blockIdx.x, tid = threadIdx.x;
    const float* xr = x + (size_t)row * DD;
    float local = 0.f;
    for (int k = tid; k < DD; k += NTHR) { float v = xr[k]; local += v * v; }
    sm[tid] = local; __syncthreads();
    for (int s = 128; s > 0; s >>= 1) { if (tid < s) sm[tid] += sm[tid + s]; __syncthreads(); }
    float scale = 1.0f / sqrtf(sm[0] / DD + EPSV);
    for (int k = tid; k < DD; k += NTHR) h[(size_t)row * DD + k] = xr[k] * scale * ln[k];
}

// -------- split-K partial GEMM: 64x64 tile over K-slice, double-buffered --
__device__ __forceinline__ void gemm_part(const float* __restrict__ A,
        const float* __restrict__ W, float* __restrict__ P,
        int K, int N, int tile, int ks, int kcnt, float* sm) {
    float* As0 = sm;                // [16][65]
    float* Ws0 = sm + 1040;        // [16][64]
    float* As1 = sm + 2064;
    float* Ws1 = sm + 3104;        // total 4128
    const int tid = threadIdx.x, tr = tid >> 4, tc = tid & 15;
    const int nb = N >> 6;
    const int row0 = (tile / nb) * 64, col0 = (tile % nb) * 64;
    const int arow = tid >> 4, acol = tid & 15;
    const int wrow = tid >> 6, wcol = tid & 63;
    const int kb = ks * kcnt * 16;
    float av[4], wv[4];
    {
        int k0 = kb;
        #pragma unroll
        for (int j = 0; j < 4; j++) {
            av[j] = A[(size_t)(row0 + arow + j * 16) * K + k0 + acol];
            wv[j] = W[(size_t)(k0 + wrow + j * 4) * N + col0 + wcol];
        }
        #pragma unroll
        for (int j = 0; j < 4; j++) {
            As0[acol * 65 + arow + j * 16] = av[j];
            Ws0[(wrow + j * 4) * 64 + wcol] = wv[j];
        }
    }
    __syncthreads();
    float acc[4][4] = {};
    for (int s = 0; s < kcnt; s++) {
        float* Ac = (s & 1) ? As1 : As0;
        float* Wc = (s & 1) ? Ws1 : Ws0;
        if (s + 1 < kcnt) {
            int k0 = kb + (s + 1) * 16;
            #pragma unroll
            for (int j = 0; j < 4; j++) {
                av[j] = A[(size_t)(row0 + arow + j * 16) * K + k0 + acol];
                wv[j] = W[(size_t)(k0 + wrow + j * 4) * N + col0 + wcol];
            }
        }
        #pragma unroll
        for (int kk = 0; kk < 16; kk++) {
            float a[4], b[4];
            #pragma unroll
            for (int j = 0; j < 4; j++) { a[j] = Ac[kk * 65 + tr * 4 + j]; b[j] = Wc[kk * 64 + tc * 4 + j]; }
            #pragma unroll
            for (int r = 0; r < 4; r++)
                #pragma unroll
                for (int c = 0; c < 4; c++) acc[r][c] += a[r] * b[c];
        }
        __syncthreads();
        if (s + 1 < kcnt) {
            float* An = (s & 1) ? As0 : As1;
            float* Wn = (s & 1) ? Ws0 : Ws1;
            #pragma unroll
            for (int j = 0; j < 4; j++) {
                An[acol * 65 + arow + j * 16] = av[j];
                Wn[(wrow + j * 4) * 64 + wcol] = wv[j];
            }
            __syncthreads();
        }
    }
    #pragma unroll
    for (int r = 0; r < 4; r++)
        #pragma unroll
        for (int c = 0; c < 4; c++)
            P[(tr * 4 + r) * 64 + tc * 4 + c] = acc[r][c];
}

template<int KS, int KCNT>
__global__ __launch_bounds__(NTHR) void k_sk(const float* __restrict__ A,
        const float* __restrict__ W, float* __restrict__ P, int K, int N) {
    __shared__ float sm[4128];
    int tile = blockIdx.x / KS, ks = blockIdx.x % KS;
    gemm_part(A, W, P + (size_t)blockIdx.x * 4096, K, N, tile, ks, KCNT, sm);
}

template<int KS, int KCNT>
__global__ __launch_bounds__(NTHR) void k_qkvsk(const float* __restrict__ A,
        const float* __restrict__ wq, const float* __restrict__ wk, const float* __restrict__ wv,
        float* __restrict__ P) {
    __shared__ float sm[4128];
    int j = blockIdx.x / KS, ks = blockIdx.x % KS;
    int m = j >> 5, t2 = j & 31;
    const float* W = (m == 0) ? wq : (m == 1 ? wk : wv);
    gemm_part(A, W, P + (size_t)blockIdx.x * 4096, 512, 512, t2, ks, KCNT, sm);
}

template<int KS, int KCNT>
__global__ __launch_bounds__(NTHR) void k_ckcvsk(const float* __restrict__ A,
        const float* __restrict__ wck, const float* __restrict__ wcv, float* __restrict__ P) {
    __shared__ float sm[4128];
    int j = blockIdx.x / KS, ks = blockIdx.x % KS;
    int m = j >> 5, t2 = j & 31;
    const float* W = (m < 2) ? (wck + (size_t)m * DD2c) : (wcv + (size_t)(m - 2) * DD2c);
    gemm_part(A, W, P + (size_t)blockIdx.x * 4096, 512, 512, t2, ks, KCNT, sm);
}

// -------- split-K reductions ----------------------------------------------
__device__ __forceinline__ void red_part(const float* __restrict__ P, float* __restrict__ C,
        const float* __restrict__ res, int N, int relu, int tile, int sidx, int KS) {
    const int tid = threadIdx.x;
    const int nb = N >> 6;
    const int row0 = (tile / nb) * 64, col0 = (tile % nb) * 64;
    const float* Pb = P + (size_t)sidx * KS * 4096;
    for (int o = tid; o < 4096; o += NTHR) {
        float v = 0.f;
        for (int k = 0; k < KS; k++) v += Pb[(size_t)k * 4096 + o];
        int r = o >> 6, c = o & 63;
        size_t ix = (size_t)(row0 + r) * N + col0 + c;
        if (res) v += res[ix];
        if (relu) v = fmaxf(v, 0.f);
        C[ix] = v;
    }
}

template<int KS>
__global__ __launch_bounds__(NTHR) void k_red(const float* __restrict__ P, float* __restrict__ C,
        const float* __restrict__ res, int N, int relu) {
    red_part(P, C, res, N, relu, blockIdx.x, blockIdx.x, KS);
}

template<int KS>
__global__ __launch_bounds__(NTHR) void k_qkvred(const float* __restrict__ P, float* __restrict__ qkv) {
    int j = blockIdx.x, m = j >> 5, t2 = j & 31;
    red_part(P, qkv + (size_t)m * BSDc, nullptr, 512, 0, t2, j, KS);
}

template<int KS>
__global__ __launch_bounds__(NTHR) void k_ckcvred(const float* __restrict__ P,
        float* __restrict__ cK, float* __restrict__ cV) {
    int j = blockIdx.x, m = j >> 5, t2 = j & 31;
    float* C = (m < 2) ? (cK + (size_t)m * BSDc) : (cV + (size_t)(m - 2) * BSDc);
    red_part(P, C, nullptr, 512, 0, t2, j, KS);
}

__global__ __launch_bounds__(NTHR) void k_eattn(const float* __restrict__ qkv,
        const float* __restrict__ mask, float* __restrict__ o) {
    __shared__ float sm[3 * 64 * 65];
    int job = blockIdx.x;
    int b = job / HH, h = job % HH;
    int tid = threadIdx.x;
    int lane = tid & 63, wave = tid >> 6;
    float* qq = sm;
    float* kk = sm + 64 * 65;
    float* vv = sm + 2 * 64 * 65;
    for (int i = tid; i < SS * DHH; i += NTHR) {
        int s = i >> 6, d = i & 63;
        size_t src = (size_t)(b * SS + s) * DD + h * DHH + d;
        qq[s * 65 + d] = qkv[src];
        kk[s * 65 + d] = qkv[BSDc + src];
        vv[s * 65 + d] = qkv[2 * BSDc + src];
    }
    __syncthreads();
    float bias = (1.0f - mask[b * SS + lane]) * NEGB;
    for (int r = 0; r < 16; r++) {
        int s = wave * 16 + r;
        float sc = 0.f;
        for (int i = 0; i < DHH; i++) sc += qq[s * 65 + i] * kk[lane * 65 + i];
        sc = sc * 0.125f + bias;
        float m = sc;
        for (int o2 = 32; o2 > 0; o2 >>= 1) m = fmaxf(m, __shfl_xor(m, o2));
        float e = expf(sc - m);
        float sum = e;
        for (int o2 = 32; o2 > 0; o2 >>= 1) sum += __shfl_xor(sum, o2);
        float p = e / sum;
        float acc = 0.f;
        for (int t2 = 0; t2 < SS; t2++) acc += __shfl(p, t2) * vv[t2 * 65 + lane];
        o[(size_t)(b * SS + s) * DD + h * DHH + lane] = acc;
    }
}

// ===================== decode building blocks =============================

// fold x0 + first nacc accumulator slots into hAT[k][b], then RMSNorm*ln
__device__ __forceinline__ void build_hAT_n(const float* __restrict__ x0,
        const float* __restrict__ accb, int nacc,
        const float* __restrict__ ln, float* hAT, float* scl) {
    const int tid = threadIdx.x, lane = tid & 63, wv = tid >> 6;
    for (int k = tid; k < DD; k += NTHR) {
        float4 h;
        h.x = x0[k]; h.y = x0[DD + k]; h.z = x0[2 * DD + k]; h.w = x0[3 * DD + k];
        for (int a = 0; a < nacc; a++) {
            const float* ap = accb + (size_t)a * 2048;
            h.x += ap[k]; h.y += ap[DD + k]; h.z += ap[2 * DD + k]; h.w += ap[3 * DD + k];
        }
        *(float4*)(hAT + (size_t)k * 4) = h;
    }
    __syncthreads();
    float loc = 0.f;
    for (int k = lane; k < DD; k += 64) { float x = hAT[k * 4 + wv]; loc += x * x; }
    for (int o = 32; o > 0; o >>= 1) loc += __shfl_xor(loc, o);
    if (lane == 0) scl[wv] = 1.0f / sqrtf(loc / DD + EPSV);
    __syncthreads();
    float s0 = scl[0], s1 = scl[1], s2 = scl[2], s3 = scl[3];
    for (int k = tid; k < DD; k += NTHR) {
        float lw = ln[k];
        float4 h = *(float4*)(hAT + (size_t)k * 4);
        h.x *= s0 * lw; h.y *= s1 * lw; h.z *= s2 * lw; h.w *= s3 * lw;
        *(float4*)(hAT + (size_t)k * 4) = h;
    }
    __syncthreads();
}

template<int K, int NC>
__device__ __forceinline__ void gemv_core(const float* hAT, const float* __restrict__ W,
        int N, int col0, float* red, float* outL) {
    constexpr int C4N = NC / 4;
    constexpr int KSN = NTHR / C4N;
    constexpr int KC  = K / KSN;
    const int tid = threadIdx.x;
    const int c4 = tid % C4N, ks = tid / C4N;
    const float4* W4 = (const float4*)W;
    float acc[4][4] = {};
    const int kb = ks * KC;
    #pragma unroll 8
    for (int kk = 0; kk < KC; kk++) {
        int k = kb + kk;
        float4 w4 = W4[(size_t)k * (N >> 2) + (col0 >> 2) + c4];
        float4 h4 = *(const float4*)(hAT + (size_t)k * 4);
        float hb[4] = {h4.x, h4.y, h4.z, h4.w};
        float wb[4] = {w4.x, w4.y, w4.z, w4.w};
        #pragma unroll
        for (int b = 0; b < 4; b++)
            #pragma unroll
            for (int ci = 0; ci < 4; ci++) acc[b][ci] += hb[b] * wb[ci];
    }
    {
        float* rp = red + (size_t)ks * (NC * 4) + c4 * 4;
        #pragma unroll
        for (int b = 0; b < 4; b++)
            #pragma unroll
            for (int ci = 0; ci < 4; ci++) rp[b * NC + ci] = acc[b][ci];
    }
    __syncthreads();
    for (int o = tid; o < 4 * NC; o += NTHR) {
        float v = 0.f;
        #pragma unroll
        for (int k2 = 0; k2 < KSN; k2++) v += red[(size_t)k2 * (NC * 4) + o];
        outL[o] = v;
    }
    __syncthreads();
}

__device__ __forceinline__ void oproj_add(const float* attT, const float* __restrict__ Wo,
        int h, float* accD, float* red) {
    const int tid = threadIdx.x;
    const int c4 = tid & 127, ks = tid >> 7;
    const float4* W4 = (const float4*)Wo;
    float ac[4][4] = {};
    const int db = ks * 32;
    #pragma unroll 8
    for (int dd = 0; dd < 32; dd++) {
        int d = db + dd;
        float4 w4 = W4[(size_t)(h * DHH + d) * 128 + c4];
        float wb[4] = {w4.x, w4.y, w4.z, w4.w};
        #pragma unroll
        for (int bb = 0; bb < 4; bb++) {
            float av = attT[d * 4 + bb];
            #pragma unroll
            for (int ci = 0; ci < 4; ci++) ac[bb][ci] += av * wb[ci];
        }
    }
    {
        float* rp = red + ks * 2048 + c4 * 4;
        #pragma unroll
        for (int bb = 0; bb < 4; bb++)
            #pragma unroll
            for (int ci = 0; ci < 4; ci++) rp[bb * 512 + ci] = ac[bb][ci];
    }
    __syncthreads();
    for (int o = tid; o < 2048; o += NTHR) {
        atomicAdd(accD + o, red[o] + red[2048 + o]);
    }
}

// fused self block (one head per block): fold -> RMS -> q/k/v -> attn -> oproj
__global__ __launch_bounds__(NTHR) void k_self(const float* __restrict__ xc,
        const float* __restrict__ accb, float* __restrict__ accw, int nacc,
        const float* __restrict__ ln1, const float* __restrict__ Wq,
        const float* __restrict__ Wk, const float* __restrict__ Wv,
        const float* __restrict__ Wso, float* __restrict__ sKl, float* __restrict__ sVl,
        int tt) {
    __shared__ float hAT[2048];
    __shared__ float red[4096];
    __shared__ float scl[4];
    __shared__ float qh[256];
    __shared__ float kh[256];
    __shared__ float vh[256];
    __shared__ float attT[256];
    const int h = blockIdx.x;
    const int tid = threadIdx.x, lane = tid & 63, b = tid >> 6;
    float* aS = accw + (size_t)nacc * 2048;

    build_hAT_n(xc, accb, nacc, ln1, hAT, scl);
    gemv_core<512, 64>(hAT, Wq, 512, h * 64, red, qh);
    gemv_core<512, 64>(hAT, Wk, 512, h * 64, red, kh);
    gemv_core<512, 64>(hAT, Wv, 512, h * 64, red, vh);
    {
        int c = tid & 63;
        size_t dst = ((size_t)b * TT + tt) * DD + h * DHH + c;
        sKl[dst] = kh[tid];
        sVl[dst] = vh[tid];
    }
    float sc = -1e30f;
    if (lane <= tt) {
        float s2 = 0.f;
        if (lane == tt) {
            #pragma unroll 16
            for (int i = 0; i < DHH; i++) s2 += qh[b * 64 + i] * kh[b * 64 + i];
        } else {
            const float* kr = sKl + ((size_t)b * TT + lane) * DD + h * DHH;
            #pragma unroll 16
            for (int i = 0; i < DHH; i++) s2 += qh[b * 64 + i] * kr[i];
        }
        sc = s2 * 0.125f;
    }
    float m = sc;
    for (int o2 = 32; o2 > 0; o2 >>= 1) m = fmaxf(m, __shfl_xor(m, o2));
    float e = (lane <= tt) ? expf(sc - m) : 0.f;
    float sum = e;
    for (int o2 = 32; o2 > 0; o2 >>= 1) sum += __shfl_xor(sum, o2);
    float pr = e / sum;
    float acc = 0.f;
    for (int j = 0; j < tt; j++) {
        float pj = __shfl(pr, j);
        acc += pj * sVl[((size_t)b * TT + j) * DD + h * DHH + lane];
    }
    acc += __shfl(pr, tt) * vh[b * 64 + lane];
    attT[lane * 4 + b] = acc;
    __syncthreads();
    oproj_add(attT, Wso, h, aS, red);
}

// fused cross block (one head per block): fold -> RMS -> q -> attn(cK,cV) -> oproj
__global__ __launch_bounds__(NTHR) void k_cross(const float* __restrict__ xc,
        const float* __restrict__ accb, float* __restrict__ accw, int nacc,
        const float* __restrict__ ln2, const float* __restrict__ Wcq,
        const float* __restrict__ Wco, const float* __restrict__ cKl,
        const float* __restrict__ cVl, const float* __restrict__ mask) {
    __shared__ float hAT[2048];
    __shared__ float red[4096];
    __shared__ float scl[4];
    __shared__ float qh[256];
    __shared__ float prS[256];
    __shared__ float attT[256];
    const int h = blockIdx.x;
    const int tid = threadIdx.x, lane = tid & 63, b = tid >> 6;
    float* aC = accw + (size_t)nacc * 2048;

    build_hAT_n(xc, accb, nacc, ln2, hAT, scl);
    gemv_core<512, 64>(hAT, Wcq, 512, h * 64, red, qh);
    const float* kr = cKl + ((size_t)b * SS + lane) * DD + h * DHH;
    float s2 = 0.f;
    #pragma unroll 16
    for (int i = 0; i < DHH; i++) s2 += qh[b * 64 + i] * kr[i];
    float sc = s2 * 0.125f + (1.0f - mask[b * SS + lane]) * NEGB;
    float m = sc;
    for (int o2 = 32; o2 > 0; o2 >>= 1) m = fmaxf(m, __shfl_xor(m, o2));
    float e = expf(sc - m);
    float sum = e;
    for (int o2 = 32; o2 > 0; o2 >>= 1) sum += __shfl_xor(sum, o2);
    prS[b * 64 + lane] = e / sum;
    const float* vbase = cVl + (size_t)b * SS * DD + h * DHH + lane;
    float a0 = 0.f, a1 = 0.f, a2 = 0.f, a3 = 0.f;
    #pragma unroll 4
    for (int j = 0; j < SS; j += 4) {
        a0 += prS[b * 64 + j]     * vbase[(size_t)j * DD];
        a1 += prS[b * 64 + j + 1] * vbase[(size_t)(j + 1) * DD];
        a2 += prS[b * 64 + j + 2] * vbase[(size_t)(j + 2) * DD];
        a3 += prS[b * 64 + j + 3] * vbase[(size_t)(j + 3) * DD];
    }
    attT[lane * 4 + b] = (a0 + a1) + (a2 + a3);
    __syncthreads();
    oproj_add(attT, Wco, h, aC, red);
}

// fused FFN block: fold -> RMS -> 16-col up-slice+ReLU -> 16-row down -> atomicAdd accF
__global__ __launch_bounds__(NTHR) void k_ffn(const float* __restrict__ xc,
        const float* __restrict__ accb, float* __restrict__ accw, int nacc,
        const float* __restrict__ ln3, const float* __restrict__ W1,
        const float* __restrict__ W2) {
    __shared__ float hAT[2048];
    __shared__ float red[4096];
    __shared__ float scl[4];
    __shared__ float upL[64];      // up-slice [b][16]
    const int j = blockIdx.x;      // 128 blocks x 16 cols
    const int tid = threadIdx.x;
    float* aF = accw + (size_t)nacc * 2048;

    build_hAT_n(xc, accb, nacc, ln3, hAT, scl);
    gemv_core<512, 16>(hAT, W1, DFFF, j * 16, red, upL);
    // down: rows j*16..+16 of W2 (512 cols each), k-split over 2 slices of 8
    {
        const int c4 = tid & 127, ks = tid >> 7;
        const float4* W24 = (const float4*)W2;
        float ac[4][4] = {};
        const int kb = ks * 8;
        #pragma unroll
        for (int kk = 0; kk < 8; kk++) {
            int row = j * 16 + kb + kk;
            float4 w4 = W24[(size_t)row * 128 + c4];
            float wb[4] = {w4.x, w4.y, w4.z, w4.w};
            #pragma unroll
            for (int bb = 0; bb < 4; bb++) {
                float av = fmaxf(upL[bb * 16 + kb + kk], 0.f);
                #pragma unroll
                for (int ci = 0; ci < 4; ci++) ac[bb][ci] += av * wb[ci];
            }
        }
        float* rp = red + ks * 2048 + c4 * 4;
        #pragma unroll
        for (int bb = 0; bb < 4; bb++)
            #pragma unroll
            for (int ci = 0; ci < 4; ci++) rp[bb * 512 + ci] = ac[bb][ci];
    }
    __syncthreads();
    for (int o0 = tid; o0 < 2048; o0 += NTHR) {
        int bb = o0 >> 9, n = (o0 + j * 16) & 511;     // stagger n to spread atomics
        int o = bb * 512 + n;
        atomicAdd(aF + o, red[o] + red[2048 + o]);
    }
}

// lm_head chunk (blocks 0..501) + stats; block 502 zeroes next-state + accs
__global__ __launch_bounds__(NTHR) void k_lmhead(const float* __restrict__ xc, float* __restrict__ xn,
        const float* __restrict__ accb, const float* __restrict__ lnf,
        const float* __restrict__ Wlm, float* __restrict__ lgb, float* __restrict__ stm,
        float* __restrict__ sts, int* __restrict__ stix, float* __restrict__ accz) {
    int blk = blockIdx.x, tid = threadIdx.x, lane = tid & 63, wave = tid >> 6;
    if (blk >= NCH) {
        for (int k = tid; k < BB * DD; k += NTHR) xn[k] = 0.f;
        for (int k = tid; k < NACCT * 2048; k += NTHR) accz[k] = 0.f;
        return;
    }
    __shared__ float hAT[2048];
    __shared__ float red[4096];
    __shared__ float msc[4];
    __shared__ float lgl[256];
    build_hAT_n(xc, accb, NACCT, lnf, hAT, msc);
    {
        int c4 = tid & 15, ks = tid >> 4;
        const float4* W4 = (const float4*)Wlm;
        float acc[4][4] = {};
        int kb = ks * 32;
        #pragma unroll
        for (int kk = 0; kk < 32; kk++) {
            int k = kb + kk;
            float4 w4 = W4[(size_t)k * (VV >> 2) + blk * 16 + c4];
            float4 h4 = *(float4*)(hAT + (size_t)k * 4);
            float hb[4] = {h4.x, h4.y, h4.z, h4.w};
            float wb[4] = {w4.x, w4.y, w4.z, w4.w};
            #pragma unroll
            for (int b = 0; b < 4; b++)
                #pragma unroll
                for (int ci = 0; ci < 4; ci++) acc[b][ci] += hb[b] * wb[ci];
        }
        float* rp = red + ks * 256 + c4 * 4;
        #pragma unroll
        for (int b = 0; b < 4; b++)
            #pragma unroll
            for (int ci = 0; ci < 4; ci++) rp[b * 64 + ci] = acc[b][ci];
    }
    __syncthreads();
    {
        float v = 0.f;
        #pragma unroll
        for (int k2 = 0; k2 < 16; k2++) v += red[k2 * 256 + tid];
        lgl[tid] = v;
        lgb[(size_t)(tid >> 6) * VV + blk * 64 + (tid & 63)] = v;
    }
    __syncthreads();
    {
        int b = wave;
        float v0 = lgl[b * 64 + lane];
        float mx = v0; int ix = lane;
        for (int o = 32; o > 0; o >>= 1) {
            float om = __shfl_xor(mx, o); int oi = __shfl_xor(ix, o);
            if (om > mx || (om == mx && oi < ix)) { mx = om; ix = oi; }
        }
        float s = expf(v0 - mx);
        for (int o = 32; o > 0; o >>= 1) s += __shfl_xor(s, o);
        if (lane == 0) {
            stm[b * STS + blk] = mx;
            sts[b * STS + blk] = s;
            stix[b * STS + blk] = blk * 64 + ix;
        }
    }
}

__global__ __launch_bounds__(NTHR) void k_dmerge(const float* __restrict__ lgb,
        const float* __restrict__ stm, const float* __restrict__ sts, const int* __restrict__ stix,
        const float* __restrict__ emb, float* __restrict__ out, float* __restrict__ xn, int tt) {
    __shared__ float mM[8];
    __shared__ int jS[4];
    __shared__ float pT[256];
    __shared__ float red[4096];
    int blk = blockIdx.x, tid = threadIdx.x, lane = tid & 63, wave = tid >> 6;
    {
        int b = wave;
        float M = -1e30f, S = 0.f; int jb = 0;
        for (int j = lane; j < NCH; j += 64) {
            float mj = stm[b * STS + j], sj = sts[b * STS + j];
            if (mj > M) { S = S * expf(M - mj) + sj; M = mj; jb = j; }
            else        { S += sj * expf(mj - M); }
        }
        for (int o = 32; o > 0; o >>= 1) {
            float Mo = __shfl_xor(M, o), So = __shfl_xor(S, o);
            int jo = __shfl_xor(jb, o);
            if (Mo > M || (Mo == M && jo < jb)) { S = S * expf(M - Mo) + So; M = Mo; jb = jo; }
            else { S += So * expf(Mo - M); }
        }
        if (lane == 0) { mM[b] = M; mM[4 + b] = S; jS[b] = jb; }
    }
    __syncthreads();
    if (blk < NCH) {
        {
            int b = tid >> 6, c = tid & 63;
            float lg = lgb[(size_t)b * VV + blk * 64 + c];
            float p = expf(lg - mM[b]) / mM[4 + b];
            out[((size_t)b * TT + tt) * VV + blk * 64 + c] = p;
            pT[c * 4 + b] = p;
        }
        __syncthreads();
        {
            int c4 = tid & 127, rs = tid >> 7;
            const float4* E4 = (const float4*)emb;
            float4 a0 = {0,0,0,0}, a1 = a0, a2 = a0, a3 = a0;
            int rb = rs * 32;
            #pragma unroll 8
            for (int r = 0; r < 32; r++) {
                int row = rb + r;
                float4 e4 = E4[((size_t)(blk * 64 + row)) * 128 + c4];
                float4 p4 = *(float4*)(pT + row * 4);
                a0.x += p4.x * e4.x; a0.y += p4.x * e4.y; a0.z += p4.x * e4.z; a0.w += p4.x * e4.w;
                a1.x += p4.y * e4.x; a1.y += p4.y * e4.y; a1.z += p4.y * e4.z; a1.w += p4.y * e4.w;
                a2.x += p4.z * e4.x; a2.y += p4.z * e4.y; a2.z += p4.z * e4.z; a2.w += p4.z * e4.w;
                a3.x += p4.w * e4.x; a3.y += p4.w * e4.y; a3.z += p4.w * e4.z; a3.w += p4.w * e4.w;
            }
            float* rp = red + rs * 2048 + c4 * 4;
            rp[0]        = a0.x; rp[1]        = a0.y; rp[2]        = a0.z; rp[3]        = a0.w;
            rp[512 + 0]  = a1.x; rp[512 + 1]  = a1.y; rp[512 + 2]  = a1.z; rp[512 + 3]  = a1.w;
            rp[1024 + 0] = a2.x; rp[1024 + 1] = a2.y; rp[1024 + 2] = a2.z; rp[1024 + 3] = a2.w;
            rp[1536 + 0] = a3.x; rp[1536 + 1] = a3.y; rp[1536 + 2] = a3.z; rp[1536 + 3] = a3.w;
        }
        __syncthreads();
        #pragma unroll
        for (int i = 0; i < 8; i++) {
            int o = tid + i * 256;
            atomicAdd(xn + o, red[o] + red[2048 + o]);
        }
    } else {
        if (tid < 4) {
            int col = stix[tid * STS + jS[tid]];
            out[(size_t)BB * TT * VV + tid * TT + tt] = (col == 0) ? 1.0f : 0.0f;
        }
    }
}

// ===================== launch =============================================
extern "C" void kernel_launch(void* const* d_in, const int* in_sizes, int n_in,
                              void* d_out, int out_size, void* d_ws, size_t ws_size,
                              hipStream_t stream) {
    const int*   ids     = (const int*)  d_in[0];
    const float* mask    = (const float*)d_in[1];
    const float* emb     = (const float*)d_in[2];
    const float* enc_wq  = (const float*)d_in[3];
    const float* enc_wk  = (const float*)d_in[4];
    const float* enc_wv  = (const float*)d_in[5];
    const float* enc_wo  = (const float*)d_in[6];
    const float* enc_ln1 = (const float*)d_in[7];
    const float* enc_w1  = (const float*)d_in[8];
    const float* enc_w2  = (const float*)d_in[9];
    const float* enc_ln2 = (const float*)d_in[10];
    const float* enc_lnf = (const float*)d_in[11];
    const float* dec_sq  = (const float*)d_in[12];
    const float* dec_sk  = (const float*)d_in[13];
    const float* dec_sv  = (const float*)d_in[14];
    const float* dec_so  = (const float*)d_in[15];
    const float* dec_ln1 = (const float*)d_in[16];
    const float* dec_cq  = (const float*)d_in[17];
    const float* dec_ck  = (const float*)d_in[18];
    const float* dec_cv  = (const float*)d_in[19];
    const float* dec_co  = (const float*)d_in[20];
    const float* dec_ln2 = (const float*)d_in[21];
    const float* dec_w1  = (const float*)d_in[22];
    const float* dec_w2  = (const float*)d_in[23];
    const float* dec_ln3 = (const float*)d_in[24];
    const float* dec_lnf = (const float*)d_in[25];
    const float* lm_head = (const float*)d_in[26];
    float* out = (float*)d_out;

    // ---- workspace layout (floats) ----
    float* ws    = (float*)d_ws;
    float* xe    = ws;                                  // 131072
    float* qkv   = xe + BSDc;                           // 393216
    float* hbuf  = qkv + 3 * BSDc;                      // 131072
    float* attb  = hbuf + BSDc;                         // 131072
    float* ffbuf = attb + BSDc;                         // 524288
    float* cK    = ffbuf + (size_t)BB * SS * DFFF;      // 262144
    float* cV    = cK + LL * BSDc;                      // 262144
    float* sK    = cV + LL * BSDc;                      // 65536
    float* sV    = sK + (size_t)LL * BB * TT * DD;      // 65536
    float* xdA   = sV + (size_t)LL * BB * TT * DD;      // 2048
    float* xdB   = xdA + 2048;                          // 2048
    float* accb  = xdB + 2048;                          // 12288 (aS,aC,aF x LL)
    float* stm   = accb + NACCT * 2048;                 // 2048
    float* sts   = stm + 4 * STS;                       // 2048
    int*   stix  = (int*)(sts + 4 * STS);               // 2048
    float* lgb   = (float*)(stix) + 2048;               // 128512 (4*VV)
    float* skb   = lgb + 4 * VV;                        // 2097152 split-K scratch

    // ---------- encoder (split-K + double-buffered GEMMs) ----------
    k_embed<<<256, NTHR, 0, stream>>>(ids, emb, xe, xdA, accb);
    for (int l = 0; l < LL; l++) {
        k_rms<<<256, NTHR, 0, stream>>>(xe, enc_ln1 + (size_t)l * DD, hbuf);
        k_qkvsk<4, 8><<<384, NTHR, 0, stream>>>(hbuf, enc_wq + (size_t)l * DD2c,
                enc_wk + (size_t)l * DD2c, enc_wv + (size_t)l * DD2c, skb);
        k_qkvred<4><<<96, NTHR, 0, stream>>>(skb, qkv);
        k_eattn<<<32, NTHR, 0, stream>>>(qkv, mask, attb);
        k_sk<8, 4><<<256, NTHR, 0, stream>>>(attb, enc_wo + (size_t)l * DD2c, skb, 512, 512);
        k_red<8><<<32, NTHR, 0, stream>>>(skb, xe, xe, 512, 0);
        k_rms<<<256, NTHR, 0, stream>>>(xe, enc_ln2 + (size_t)l * DD, hbuf);
        k_sk<4, 8><<<512, NTHR, 0, stream>>>(hbuf, enc_w1 + (size_t)l * DD * DFFF, skb, 512, 2048);
        k_red<4><<<128, NTHR, 0, stream>>>(skb, ffbuf, nullptr, 2048, 1);
        k_sk<16, 8><<<512, NTHR, 0, stream>>>(ffbuf, enc_w2 + (size_t)l * DFFF * DD, skb, 2048, 512);
        k_red<16><<<32, NTHR, 0, stream>>>(skb, xe, xe, 512, 0);
    }
    k_rms<<<256, NTHR, 0, stream>>>(xe, enc_lnf, hbuf);
    k_ckcvsk<4, 8><<<512, NTHR, 0, stream>>>(hbuf, dec_ck, dec_cv, skb);
    k_ckcvred<4><<<128, NTHR, 0, stream>>>(skb, cK, cV);

    // ---------- decode (fused FFN, prefix-fold accumulators) ----------
    for (int tt = 0; tt < TT; tt++) {
        float* xc = (tt & 1) ? xdB : xdA;
        float* xn = (tt & 1) ? xdA : xdB;
        for (int l = 0; l < LL; l++) {
            k_self<<<HH, NTHR, 0, stream>>>(xc, accb, accb, 3 * l,
                    dec_ln1 + (size_t)l * DD,
                    dec_sq + (size_t)l * DD2c, dec_sk + (size_t)l * DD2c,
                    dec_sv + (size_t)l * DD2c, dec_so + (size_t)l * DD2c,
                    sK + (size_t)l * BB * TT * DD, sV + (size_t)l * BB * TT * DD, tt);
            k_cross<<<HH, NTHR, 0, stream>>>(xc, accb, accb, 3 * l + 1,
                    dec_ln2 + (size_t)l * DD,
                    dec_cq + (size_t)l * DD2c, dec_co + (size_t)l * DD2c,
                    cK + (size_t)l * BSDc, cV + (size_t)l * BSDc, mask);
            k_ffn<<<128, NTHR, 0, stream>>>(xc, accb, accb, 3 * l + 2,
                    dec_ln3 + (size_t)l * DD,
                    dec_w1 + (size_t)l * DD * DFFF, dec_w2 + (size_t)l * DFFF * DD);
        }
        k_lmhead<<<NCH + 1, NTHR, 0, stream>>>(xc, xn, accb, dec_lnf, lm_head,
                lgb, stm, sts, stix, accb);
        k_dmerge<<<NCH + 1, NTHR, 0, stream>>>(lgb, stm, sts, stix, emb, out, xn, tt);
    }
}